// Round 1
// baseline (1988.030 us; speedup 1.0000x reference)
//
#include <hip/hip_runtime.h>

// ---------------- problem constants ----------------
#define N_TOK   16384        // B*H*W = 16*32*32
#define K_CODES 8192
#define DIMS    256

// d_out offsets (in floats), concatenated return order:
// out, loss, idx, new_cluster_size, new_ema_w, new_embedding
#define OUT_OFF  0
#define LOSS_OFF 4194304
#define IDX_OFF  4194305
#define NCS_OFF  4210689
#define NEMA_OFF 4218881
#define NEMB_OFF 6316033

// ws byte offsets
#define WS_COUNTS 0          // f32 [8192]
#define WS_ENORM  32768      // f32 [8192]
#define WS_CS     65536      // f32 [8192]
#define WS_IDXI   98304      // int [16384]
#define WS_PVAL   163840     // f32 [2][16384]
#define WS_PIDX   294912     // int [2][16384]
#define WS_DENOM  425984     // double [1]

// ---------------- kernels ----------------

// ||e_k||^2 in fp64, rounded to f32 (low error -> tracks true argmin)
__global__ __launch_bounds__(256) void enorm_kernel(const float* __restrict__ emb,
                                                    float* __restrict__ enorm) {
    __shared__ double red[256];
    const int k = blockIdx.x, tid = threadIdx.x;
    const float v = emb[(size_t)k * DIMS + tid];
    red[tid] = (double)v * (double)v;
    __syncthreads();
    for (int s = 128; s; s >>= 1) {
        if (tid < s) red[tid] += red[tid + s];
        __syncthreads();
    }
    if (tid == 0) enorm[k] = (float)red[0];
}

// Tiled GEMM + argmin. Grid: 256 token-tiles x 2 code-halves = 512 blocks.
// Tile: 64 tokens x 64 codes, thread = 4x4 micro-tile, K staged in 32-chunks.
__global__ __launch_bounds__(256) void argmin_kernel(
    const float* __restrict__ z,       // [16][256][1024]
    const float* __restrict__ emb,     // [8192][256]
    const float* __restrict__ enorm,   // [8192]
    float* __restrict__ pval, int* __restrict__ pidx) {
    __shared__ float Zs[32][64];   // [dim-chunk][token]
    __shared__ float Es[32][68];   // [dim-chunk][code], pad 68 (16B-aligned rows)

    const int tid  = threadIdx.x;
    const int tile = blockIdx.x >> 1;
    const int half = blockIdx.x & 1;
    const int t0   = tile * 64;
    const int b    = t0 >> 10;
    const int hw0  = t0 & 1023;
    const float* zbase = z + ((size_t)b << 18) + hw0;

    const int ty = tid >> 4;   // 0..15 -> tokens ty*4..+3
    const int tx = tid & 15;   // codes tx*4..+3 within code tile

    float bestv[4];
    int   besti[4];
#pragma unroll
    for (int i = 0; i < 4; ++i) { bestv[i] = 3.4e38f; besti[i] = 0; }

    const int k_begin = half * (K_CODES / 2);
    const int k_end   = k_begin + (K_CODES / 2);

    for (int kt = k_begin; kt < k_end; kt += 64) {
        float acc[4][4] = {{0.f, 0.f, 0.f, 0.f}, {0.f, 0.f, 0.f, 0.f},
                           {0.f, 0.f, 0.f, 0.f}, {0.f, 0.f, 0.f, 0.f}};
        for (int d0 = 0; d0 < DIMS; d0 += 32) {
            __syncthreads();
            {   // stage Z chunk: coalesced 64-float rows
                const int lane = tid & 63, dq = tid >> 6;
#pragma unroll
                for (int dd = dq; dd < 32; dd += 4)
                    Zs[dd][lane] = zbase[(size_t)(d0 + dd) << 10 | (unsigned)lane];
            }
            {   // stage E chunk: coalesced 32-float segments per code row
                const int dd = tid & 31, j0 = tid >> 5;
#pragma unroll
                for (int j = j0; j < 64; j += 8)
                    Es[dd][j] = emb[(size_t)(kt + j) * DIMS + d0 + dd];
            }
            __syncthreads();
#pragma unroll
            for (int dd = 0; dd < 32; ++dd) {
                const float4 a  = *(const float4*)&Zs[dd][ty * 4];
                const float4 e4 = *(const float4*)&Es[dd][tx * 4];
                acc[0][0] += a.x * e4.x; acc[0][1] += a.x * e4.y;
                acc[0][2] += a.x * e4.z; acc[0][3] += a.x * e4.w;
                acc[1][0] += a.y * e4.x; acc[1][1] += a.y * e4.y;
                acc[1][2] += a.y * e4.z; acc[1][3] += a.y * e4.w;
                acc[2][0] += a.z * e4.x; acc[2][1] += a.z * e4.y;
                acc[2][2] += a.z * e4.z; acc[2][3] += a.z * e4.w;
                acc[3][0] += a.w * e4.x; acc[3][1] += a.w * e4.y;
                acc[3][2] += a.w * e4.z; acc[3][3] += a.w * e4.w;
            }
        }
        // score = ||e||^2 - 2 z.e ; update running argmin (k ascending, strict <)
#pragma unroll
        for (int j = 0; j < 4; ++j) {
            const int k = kt + tx * 4 + j;
            const float en = enorm[k];
#pragma unroll
            for (int i = 0; i < 4; ++i) {
                const float s = en - 2.0f * acc[i][j];
                if (s < bestv[i]) { bestv[i] = s; besti[i] = k; }
            }
        }
    }
    // reduce across tx (16-lane subgroups share the same 4 tokens)
#pragma unroll
    for (int off = 8; off; off >>= 1) {
#pragma unroll
        for (int i = 0; i < 4; ++i) {
            const float ov = __shfl_down(bestv[i], off, 16);
            const int   oi = __shfl_down(besti[i], off, 16);
            if (ov < bestv[i] || (ov == bestv[i] && oi < besti[i])) {
                bestv[i] = ov; besti[i] = oi;
            }
        }
    }
    if (tx == 0) {
#pragma unroll
        for (int i = 0; i < 4; ++i) {
            const int n = t0 + ty * 4 + i;
            pval[half * N_TOK + n] = bestv[i];
            pidx[half * N_TOK + n] = besti[i];
        }
    }
}

__global__ __launch_bounds__(256) void combine_kernel(
    const float* __restrict__ pval, const int* __restrict__ pidx,
    int* __restrict__ idx_i, float* __restrict__ idx_f) {
    const int n = blockIdx.x * 256 + threadIdx.x;
    const float v0 = pval[n], v1 = pval[N_TOK + n];
    const int i0 = pidx[n], i1 = pidx[N_TOK + n];
    const int best = (v1 < v0 || (v1 == v0 && i1 < i0)) ? i1 : i0;
    idx_i[n] = best;
    idx_f[n] = (float)best;
}

// z_q gather/transpose + loss + counts + 0.01*embed_sum accumulated into NEMA
__global__ __launch_bounds__(256) void gather_kernel(
    const float* __restrict__ z, const float* __restrict__ emb,
    const int* __restrict__ idx_i, float* __restrict__ out,
    float* __restrict__ loss_cell, float* __restrict__ counts,
    float* __restrict__ nema_acc) {
    const int tid = threadIdx.x;
    const int n0 = blockIdx.x * 64;
    const int b = n0 >> 10, hw0 = n0 & 1023;
    const int lane = tid & 63, w = tid >> 6;
    const int n = n0 + lane;
    const int k = idx_i[n];
    if (w == 0) atomicAdd(&counts[k], 1.0f);
    const float* zb = z + ((size_t)b << 18) + hw0 + lane;
    float* ob = out + ((size_t)b << 18) + hw0 + lane;
    float ls = 0.f;
#pragma unroll 4
    for (int d = w; d < DIMS; d += 4) {
        const float zv = zb[(size_t)d << 10];
        const float ev = emb[((size_t)k << 8) + d];
        ob[(size_t)d << 10] = ev;
        const float df = ev - zv;
        ls += df * df;
        atomicAdd(&nema_acc[((size_t)k << 8) + d], 0.01f * zv);
    }
    __shared__ float red[256];
    red[tid] = ls;
    __syncthreads();
    for (int s = 128; s; s >>= 1) {
        if (tid < s) red[tid] += red[tid + s];
        __syncthreads();
    }
    if (tid == 0) atomicAdd(loss_cell, red[0] * (0.25f / 4194304.0f));
}

// cs = 0.99*cluster_size + 0.01*counts + eps; accumulate fp64 denom
__global__ __launch_bounds__(256) void cs_kernel(
    const float* __restrict__ cluster_size, const float* __restrict__ counts,
    float* __restrict__ cs, double* __restrict__ denom) {
    const int tid = threadIdx.x;
    const int k = blockIdx.x * 256 + tid;
    const float v = cluster_size[k] * 0.99f + 0.01f * counts[k] + 1e-5f;
    cs[k] = v;
    __shared__ double red[256];
    red[tid] = (double)v;
    __syncthreads();
    for (int s = 128; s; s >>= 1) {
        if (tid < s) red[tid] += red[tid + s];
        __syncthreads();
    }
    if (tid == 0) atomicAdd(denom, red[0]);
}

// ncs = cs/denom ; new_ema_w = 0.99*ema_w + (0.01*embed_sum already in NEMA);
// new_embedding = new_ema_w / ncs
__global__ __launch_bounds__(256) void finalize_kernel(
    const float* __restrict__ ema_w, const float* __restrict__ cs,
    const double* __restrict__ denom, float* __restrict__ ncs_out,
    float* __restrict__ nema_out, float* __restrict__ nemb_out) {
    const int k = blockIdx.x, d = threadIdx.x;
    const float dn = (float)(*denom) + (float)K_CODES * 1e-5f;
    const float ncs = cs[k] / dn;
    if (d == 0) ncs_out[k] = ncs;
    const size_t off = ((size_t)k << 8) + d;
    const float ne = ema_w[off] * 0.99f + nema_out[off];
    nema_out[off] = ne;
    nemb_out[off] = ne / ncs;
}

// ---------------- launch ----------------
extern "C" void kernel_launch(void* const* d_in, const int* in_sizes, int n_in,
                              void* d_out, int out_size, void* d_ws, size_t ws_size,
                              hipStream_t stream) {
    const float* z            = (const float*)d_in[0];
    const float* emb          = (const float*)d_in[1];
    const float* cluster_size = (const float*)d_in[2];
    const float* ema_w        = (const float*)d_in[3];
    float* out = (float*)d_out;
    char*  wsb = (char*)d_ws;

    float*  counts = (float*)(wsb + WS_COUNTS);
    float*  enorm  = (float*)(wsb + WS_ENORM);
    float*  cs     = (float*)(wsb + WS_CS);
    int*    idx_i  = (int*)(wsb + WS_IDXI);
    float*  pval   = (float*)(wsb + WS_PVAL);
    int*    pidx   = (int*)(wsb + WS_PIDX);
    double* denom  = (double*)(wsb + WS_DENOM);

    // zero: loss cell, new_ema_w region (atomic accumulator), counts, denom
    hipMemsetAsync((char*)d_out + (size_t)LOSS_OFF * 4, 0, 4, stream);
    hipMemsetAsync((char*)d_out + (size_t)NEMA_OFF * 4, 0, (size_t)2097152 * 4, stream);
    hipMemsetAsync(wsb + WS_COUNTS, 0, 32768, stream);
    hipMemsetAsync(wsb + WS_DENOM, 0, 8, stream);

    enorm_kernel<<<K_CODES, 256, 0, stream>>>(emb, enorm);
    argmin_kernel<<<512, 256, 0, stream>>>(z, emb, enorm, pval, pidx);
    combine_kernel<<<N_TOK / 256, 256, 0, stream>>>(pval, pidx, idx_i,
                                                    out + IDX_OFF);
    gather_kernel<<<N_TOK / 64, 256, 0, stream>>>(z, emb, idx_i, out + OUT_OFF,
                                                  out + LOSS_OFF, counts,
                                                  out + NEMA_OFF);
    cs_kernel<<<K_CODES / 256, 256, 0, stream>>>(cluster_size, counts, cs, denom);
    finalize_kernel<<<K_CODES, 256, 0, stream>>>(ema_w, cs, denom, out + NCS_OFF,
                                                 out + NEMA_OFF, out + NEMB_OFF);
}

// Round 2
// 1351.388 us; speedup vs baseline: 1.4711x; 1.4711x over previous
//
#include <hip/hip_runtime.h>

#define N_TOK   16384
#define K_CODES 8192
#define DIMS    256

// d_out offsets (floats): out, loss, idx, new_cluster_size, new_ema_w, new_embedding
#define OUT_OFF  0
#define LOSS_OFF 4194304
#define IDX_OFF  4194305
#define NCS_OFF  4210689
#define NEMA_OFF 4218881
#define NEMB_OFF 6316033

// ws byte offsets
#define WS_ZH     0u          // ushort [16384][256]  8 MB  (token-major, transposed)
#define WS_ZL     8388608u    // ushort [16384][256]  8 MB
#define WS_EH     16777216u   // ushort [8192][256]   4 MB
#define WS_EL     20971520u   // ushort [8192][256]   4 MB
#define WS_ENORM  25165824u   // f32 [8192]
#define WS_PVAL   25198592u   // f32 [4][16384]
#define WS_PIDX   25460736u   // int [4][16384]
#define WS_IDXI   25722880u   // int [16384]
#define WS_COUNTS 25788416u   // f32 [8192]
#define WS_CS     25821184u   // f32 [8192]
#define WS_DENOM  25853952u   // double

typedef _Float16 f16x8 __attribute__((ext_vector_type(8)));
typedef float    f32x16 __attribute__((ext_vector_type(16)));

union HU { _Float16 h; unsigned short u; };

static __device__ inline void split_f32(float x, unsigned short& hi, unsigned short& lo) {
    HU a; a.h = (_Float16)x;                    // RNE f32->f16
    float r = (x - (float)a.h) * 2048.0f;       // exact residual, scaled to normal range
    HU b; b.h = (_Float16)r;
    hi = a.u; lo = b.u;
}

// ---- conversion: emb [8192][256] f32 -> eh/el (same layout) ----
__global__ __launch_bounds__(256) void cvt_e_kernel(const float* __restrict__ emb,
                                                    unsigned short* __restrict__ eh,
                                                    unsigned short* __restrict__ el) {
    const int i = blockIdx.x * 256 + threadIdx.x;   // float4 index
    const float4 v = ((const float4*)emb)[i];
    const float vv[4] = {v.x, v.y, v.z, v.w};
    ushort4 h, l;
    unsigned short* hp = &h.x; unsigned short* lp = &l.x;
#pragma unroll
    for (int j = 0; j < 4; ++j) split_f32(vv[j], hp[j], lp[j]);
    ((ushort4*)eh)[i] = h;
    ((ushort4*)el)[i] = l;
}

// ---- conversion: z [16][256][1024] f32 -> zh/zl [token][dim] (transpose) ----
__global__ __launch_bounds__(256) void cvt_z_kernel(const float* __restrict__ z,
                                                    unsigned short* __restrict__ zh,
                                                    unsigned short* __restrict__ zl) {
    const int i = blockIdx.x * 256 + threadIdx.x;   // float4 index in z layout
    const int e0 = i * 4;
    const int hw = e0 & 1023;
    const int bd = e0 >> 10;
    const int d = bd & 255, b = bd >> 8;
    const float4 v = ((const float4*)z)[i];
    const float vv[4] = {v.x, v.y, v.z, v.w};
    const int tok0 = b * 1024 + hw;
#pragma unroll
    for (int j = 0; j < 4; ++j) {
        unsigned short h, l;
        split_f32(vv[j], h, l);
        zh[(size_t)(tok0 + j) * 256 + d] = h;
        zl[(size_t)(tok0 + j) * 256 + d] = l;
    }
}

// ---- ||e_k||^2 in fp64 -> f32 ----
__global__ __launch_bounds__(256) void enorm_kernel(const float* __restrict__ emb,
                                                    float* __restrict__ enorm) {
    __shared__ double red[256];
    const int k = blockIdx.x, tid = threadIdx.x;
    const float v = emb[(size_t)k * DIMS + tid];
    red[tid] = (double)v * (double)v;
    __syncthreads();
    for (int s = 128; s; s >>= 1) {
        if (tid < s) red[tid] += red[tid + s];
        __syncthreads();
    }
    if (tid == 0) enorm[k] = (float)red[0];
}

// ---- MFMA argmin: D[code][token], block = 128 tokens x 2048-code split ----
__global__ __launch_bounds__(256, 2) void argmin_mfma(
    const unsigned short* __restrict__ zh, const unsigned short* __restrict__ zl,
    const unsigned short* __restrict__ eh, const unsigned short* __restrict__ el,
    const float* __restrict__ enorm, float* __restrict__ pval, int* __restrict__ pidx) {
    __shared__ __align__(16) unsigned short Es[16384];  // lv(2) x it(4) x kseg(8) x m(32) x 8
    __shared__ __align__(16) unsigned short Zs[16384];
    __shared__ float en_s[128];
    __shared__ float redv[2][128];
    __shared__ int   redi[2][128];

    const int tid = threadIdx.x;
    const int lane = tid & 63, wave = tid >> 6;
    const int mw = wave >> 1, nw = wave & 1;     // mw: code-half, nw: token-half
    const int tile = blockIdx.x >> 2, csplit = blockIdx.x & 3;
    const int token0 = tile * 128, code0 = csplit * 2048;

    // staging mapping: thread -> (kseg, crow); unit = ((lv*4+it)*8+kseg)*32+crow
    const int kseg = tid & 7;
    const int crow = tid >> 3;                   // 0..31
    const unsigned short* ebase[2] = {eh, el};
    const unsigned short* zbase[2] = {zh, zl};

    // frag read offsets (ushort index): lane-contiguous 16B
    const int khalf = lane >> 5, fm = lane & 31;
    int eoff[2][2], zoff[2][2];
#pragma unroll
    for (int lv = 0; lv < 2; ++lv)
#pragma unroll
        for (int t = 0; t < 2; ++t) {
            eoff[lv][t] = (((lv * 4 + (mw * 2 + t)) * 8 + khalf) * 32 + fm) * 8;
            zoff[lv][t] = (((lv * 4 + (nw * 2 + t)) * 8 + khalf) * 32 + fm) * 8;
        }

    float bv[2] = {3.4e38f, 3.4e38f};
    int   bi[2] = {0, 0};

    uint4 Ep[2][4], Zp[2][4];
    {   // prefetch chunk 0 (ct=0, kc=0)
#pragma unroll
        for (int lv = 0; lv < 2; ++lv)
#pragma unroll
            for (int it = 0; it < 4; ++it) {
                Ep[lv][it] = *(const uint4*)(ebase[lv] + (size_t)(code0 + crow + it * 32) * 256 + kseg * 8);
                Zp[lv][it] = *(const uint4*)(zbase[lv] + (size_t)(token0 + crow + it * 32) * 256 + kseg * 8);
            }
    }

    f32x16 acc_h[2][2], acc_l[2][2];

    for (int ct = 0; ct < 16; ++ct) {
#pragma unroll
        for (int mt = 0; mt < 2; ++mt)
#pragma unroll
            for (int nt = 0; nt < 2; ++nt)
#pragma unroll
                for (int q = 0; q < 16; ++q) { acc_h[mt][nt][q] = 0.f; acc_l[mt][nt][q] = 0.f; }

        for (int kc = 0; kc < 4; ++kc) {
            __syncthreads();
#pragma unroll
            for (int lv = 0; lv < 2; ++lv)
#pragma unroll
                for (int it = 0; it < 4; ++it) {
                    *(uint4*)(&Es[(((lv * 4 + it) * 8 + kseg) * 32 + crow) * 8]) = Ep[lv][it];
                    *(uint4*)(&Zs[(((lv * 4 + it) * 8 + kseg) * 32 + crow) * 8]) = Zp[lv][it];
                }
            if (kc == 0 && tid < 128) en_s[tid] = enorm[code0 + ct * 128 + tid];
            __syncthreads();

            // prefetch next chunk (overlaps with MFMA below)
            const int nchunk = ct * 4 + kc + 1;
            if (nchunk < 64) {
                const int nct = nchunk >> 2, nkc = nchunk & 3;
#pragma unroll
                for (int lv = 0; lv < 2; ++lv)
#pragma unroll
                    for (int it = 0; it < 4; ++it) {
                        Ep[lv][it] = *(const uint4*)(ebase[lv] + (size_t)(code0 + nct * 128 + crow + it * 32) * 256 + nkc * 64 + kseg * 8);
                        Zp[lv][it] = *(const uint4*)(zbase[lv] + (size_t)(token0 + crow + it * 32) * 256 + nkc * 64 + kseg * 8);
                    }
            }

#pragma unroll
            for (int ks = 0; ks < 4; ++ks) {
                const int ko = ks * 512;
                f16x8 ae[2][2], bz[2][2];
#pragma unroll
                for (int lv = 0; lv < 2; ++lv)
#pragma unroll
                    for (int t = 0; t < 2; ++t) {
                        ae[lv][t] = *(const f16x8*)(&Es[eoff[lv][t] + ko]);
                        bz[lv][t] = *(const f16x8*)(&Zs[zoff[lv][t] + ko]);
                    }
#pragma unroll
                for (int mt = 0; mt < 2; ++mt)
#pragma unroll
                    for (int nt = 0; nt < 2; ++nt) {
                        acc_h[mt][nt] = __builtin_amdgcn_mfma_f32_32x32x16_f16(ae[0][mt], bz[0][nt], acc_h[mt][nt], 0, 0, 0);
                        acc_l[mt][nt] = __builtin_amdgcn_mfma_f32_32x32x16_f16(ae[0][mt], bz[1][nt], acc_l[mt][nt], 0, 0, 0);
                        acc_l[mt][nt] = __builtin_amdgcn_mfma_f32_32x32x16_f16(ae[1][mt], bz[0][nt], acc_l[mt][nt], 0, 0, 0);
                    }
            }
        }
        // epilogue: score = ||e||^2 - 2*(hi + lo/2048); running per-lane argmin
        const int rbase = 4 * khalf;
#pragma unroll
        for (int nt = 0; nt < 2; ++nt)
#pragma unroll
            for (int mt = 0; mt < 2; ++mt)
#pragma unroll
                for (int r = 0; r < 16; ++r) {
                    const int il = mw * 64 + mt * 32 + (r & 3) + 8 * (r >> 2) + rbase;
                    const float s = en_s[il] - 2.0f * (acc_h[mt][nt][r] + acc_l[mt][nt][r] * 4.8828125e-4f);
                    const int code = code0 + ct * 128 + il;
                    if (s < bv[nt]) { bv[nt] = s; bi[nt] = code; }
                }
    }

    // combine lane-halves (codes interleaved: tie-break on idx)
#pragma unroll
    for (int nt = 0; nt < 2; ++nt) {
        const float ov = __shfl_xor(bv[nt], 32);
        const int   oi = __shfl_xor(bi[nt], 32);
        if (ov < bv[nt] || (ov == bv[nt] && oi < bi[nt])) { bv[nt] = ov; bi[nt] = oi; }
        if (lane < 32) {
            const int tl = nw * 64 + nt * 32 + lane;
            redv[mw][tl] = bv[nt]; redi[mw][tl] = bi[nt];
        }
    }
    __syncthreads();
    if (tid < 128) {
        const float v0 = redv[0][tid], v1 = redv[1][tid];
        const int i0 = redi[0][tid], i1 = redi[1][tid];
        const bool t2 = (v1 < v0) || (v1 == v0 && i1 < i0);
        pval[csplit * N_TOK + token0 + tid] = t2 ? v1 : v0;
        pidx[csplit * N_TOK + token0 + tid] = t2 ? i1 : i0;
    }
}

// ---- combine 4 code-split partials ----
__global__ __launch_bounds__(256) void combine4_kernel(
    const float* __restrict__ pval, const int* __restrict__ pidx,
    int* __restrict__ idx_i, float* __restrict__ idx_f) {
    const int n = blockIdx.x * 256 + threadIdx.x;
    float bv = pval[n]; int bi = pidx[n];
#pragma unroll
    for (int s = 1; s < 4; ++s) {
        const float v = pval[s * N_TOK + n];
        const int i = pidx[s * N_TOK + n];
        if (v < bv || (v == bv && i < bi)) { bv = v; bi = i; }
    }
    idx_i[n] = bi;
    idx_f[n] = (float)bi;
}

// ---- z_q gather/transpose + loss + counts + 0.01*embed_sum into NEMA ----
__global__ __launch_bounds__(256) void gather_kernel(
    const float* __restrict__ z, const float* __restrict__ emb,
    const int* __restrict__ idx_i, float* __restrict__ out,
    float* __restrict__ loss_cell, float* __restrict__ counts,
    float* __restrict__ nema_acc) {
    const int tid = threadIdx.x;
    const int n0 = blockIdx.x * 64;
    const int b = n0 >> 10, hw0 = n0 & 1023;
    const int lane = tid & 63, w = tid >> 6;
    const int n = n0 + lane;
    const int k = idx_i[n];
    if (w == 0) atomicAdd(&counts[k], 1.0f);
    const float* zb = z + ((size_t)b << 18) + hw0 + lane;
    float* ob = out + ((size_t)b << 18) + hw0 + lane;
    float ls = 0.f;
#pragma unroll 4
    for (int d = w; d < DIMS; d += 4) {
        const float zv = zb[(size_t)d << 10];
        const float ev = emb[((size_t)k << 8) + d];
        ob[(size_t)d << 10] = ev;
        const float df = ev - zv;
        ls += df * df;
        atomicAdd(&nema_acc[((size_t)k << 8) + d], 0.01f * zv);
    }
    __shared__ float red[256];
    red[tid] = ls;
    __syncthreads();
    for (int s = 128; s; s >>= 1) {
        if (tid < s) red[tid] += red[tid + s];
        __syncthreads();
    }
    if (tid == 0) atomicAdd(loss_cell, red[0] * (0.25f / 4194304.0f));
}

// ---- cs + fp64 denom ----
__global__ __launch_bounds__(256) void cs_kernel(
    const float* __restrict__ cluster_size, const float* __restrict__ counts,
    float* __restrict__ cs, double* __restrict__ denom) {
    const int tid = threadIdx.x;
    const int k = blockIdx.x * 256 + tid;
    const float v = cluster_size[k] * 0.99f + 0.01f * counts[k] + 1e-5f;
    cs[k] = v;
    __shared__ double red[256];
    red[tid] = (double)v;
    __syncthreads();
    for (int s = 128; s; s >>= 1) {
        if (tid < s) red[tid] += red[tid + s];
        __syncthreads();
    }
    if (tid == 0) atomicAdd(denom, red[0]);
}

// ---- finalize ----
__global__ __launch_bounds__(256) void finalize_kernel(
    const float* __restrict__ ema_w, const float* __restrict__ cs,
    const double* __restrict__ denom, float* __restrict__ ncs_out,
    float* __restrict__ nema_out, float* __restrict__ nemb_out) {
    const int k = blockIdx.x, d = threadIdx.x;
    const float dn = (float)(*denom) + (float)K_CODES * 1e-5f;
    const float ncs = cs[k] / dn;
    if (d == 0) ncs_out[k] = ncs;
    const size_t off = ((size_t)k << 8) + d;
    const float ne = ema_w[off] * 0.99f + nema_out[off];
    nema_out[off] = ne;
    nemb_out[off] = ne / ncs;
}

// ---------------- launch ----------------
extern "C" void kernel_launch(void* const* d_in, const int* in_sizes, int n_in,
                              void* d_out, int out_size, void* d_ws, size_t ws_size,
                              hipStream_t stream) {
    const float* z            = (const float*)d_in[0];
    const float* emb          = (const float*)d_in[1];
    const float* cluster_size = (const float*)d_in[2];
    const float* ema_w        = (const float*)d_in[3];
    float* out = (float*)d_out;
    char*  wsb = (char*)d_ws;

    unsigned short* zh = (unsigned short*)(wsb + WS_ZH);
    unsigned short* zl = (unsigned short*)(wsb + WS_ZL);
    unsigned short* eh = (unsigned short*)(wsb + WS_EH);
    unsigned short* el = (unsigned short*)(wsb + WS_EL);
    float*  enorm  = (float*)(wsb + WS_ENORM);
    float*  pval   = (float*)(wsb + WS_PVAL);
    int*    pidx   = (int*)(wsb + WS_PIDX);
    int*    idx_i  = (int*)(wsb + WS_IDXI);
    float*  counts = (float*)(wsb + WS_COUNTS);
    float*  cs     = (float*)(wsb + WS_CS);
    double* denom  = (double*)(wsb + WS_DENOM);

    hipMemsetAsync((char*)d_out + (size_t)LOSS_OFF * 4, 0, 4, stream);
    hipMemsetAsync((char*)d_out + (size_t)NEMA_OFF * 4, 0, (size_t)2097152 * 4, stream);
    hipMemsetAsync(wsb + WS_COUNTS, 0, 32768, stream);
    hipMemsetAsync(wsb + WS_DENOM, 0, 8, stream);

    cvt_z_kernel<<<4096, 256, 0, stream>>>(z, zh, zl);
    cvt_e_kernel<<<2048, 256, 0, stream>>>(emb, eh, el);
    enorm_kernel<<<K_CODES, 256, 0, stream>>>(emb, enorm);
    argmin_mfma<<<512, 256, 0, stream>>>(zh, zl, eh, el, enorm, pval, pidx);
    combine4_kernel<<<N_TOK / 256, 256, 0, stream>>>(pval, pidx, idx_i, out + IDX_OFF);
    gather_kernel<<<N_TOK / 64, 256, 0, stream>>>(z, emb, idx_i, out + OUT_OFF,
                                                  out + LOSS_OFF, counts, out + NEMA_OFF);
    cs_kernel<<<K_CODES / 256, 256, 0, stream>>>(cluster_size, counts, cs, denom);
    finalize_kernel<<<K_CODES, 256, 0, stream>>>(ema_w, cs, denom, out + NCS_OFF,
                                                 out + NEMA_OFF, out + NEMB_OFF);
}

// Round 3
// 849.737 us; speedup vs baseline: 2.3396x; 1.5904x over previous
//
#include <hip/hip_runtime.h>

#define N_TOK   16384
#define K_CODES 8192
#define DIMS    256

// d_out offsets (floats): out, loss, idx, new_cluster_size, new_ema_w, new_embedding
#define OUT_OFF  0
#define LOSS_OFF 4194304
#define IDX_OFF  4194305
#define NCS_OFF  4210689
#define NEMA_OFF 4218881
#define NEMB_OFF 6316033

// ws byte offsets
#define WS_ZH     0u          // ushort [16384][256]  8 MB  (token-major, transposed)
#define WS_ZL     8388608u    // ushort [16384][256]  8 MB
#define WS_EH     16777216u   // ushort [8192][256]   4 MB
#define WS_EL     20971520u   // ushort [8192][256]   4 MB
#define WS_ENORM  25165824u   // f32 [8192]
#define WS_PVAL   25198592u   // f32 [4][16384]
#define WS_PIDX   25460736u   // int [4][16384]
#define WS_IDXI   25722880u   // int [16384]
#define WS_COUNTS 25788416u   // f32 [8192]
#define WS_CS     25821184u   // f32 [8192]
#define WS_DENOM  25853952u   // double

typedef _Float16 f16x8 __attribute__((ext_vector_type(8)));
typedef float    f32x16 __attribute__((ext_vector_type(16)));

union HU { _Float16 h; unsigned short u; };

static __device__ inline void split_f32(float x, unsigned short& hi, unsigned short& lo) {
    HU a; a.h = (_Float16)x;                    // RNE f32->f16
    float r = (x - (float)a.h) * 2048.0f;       // exact residual, scaled to normal range
    HU b; b.h = (_Float16)r;
    hi = a.u; lo = b.u;
}

// async global->LDS, 16B per lane; LDS dest = wave-uniform base + lane*16
#define GLD16(gp, lp) __builtin_amdgcn_global_load_lds( \
    (const __attribute__((address_space(1))) unsigned int*)(gp), \
    (__attribute__((address_space(3))) unsigned int*)(lp), 16, 0, 0)

// ---- conversion: emb [8192][256] f32 -> eh/el (same layout) ----
__global__ __launch_bounds__(256) void cvt_e_kernel(const float* __restrict__ emb,
                                                    unsigned short* __restrict__ eh,
                                                    unsigned short* __restrict__ el) {
    const int i = blockIdx.x * 256 + threadIdx.x;   // float4 index
    const float4 v = ((const float4*)emb)[i];
    const float vv[4] = {v.x, v.y, v.z, v.w};
    ushort4 h, l;
    unsigned short* hp = &h.x; unsigned short* lp = &l.x;
#pragma unroll
    for (int j = 0; j < 4; ++j) split_f32(vv[j], hp[j], lp[j]);
    ((ushort4*)eh)[i] = h;
    ((ushort4*)el)[i] = l;
}

// ---- conversion: z [16][256][1024] f32 -> zh/zl [token][dim], LDS transpose ----
// grid: b(16) x dg(4) x hg(16) = 1024 blocks; tile = 64 dims x 64 hw
__global__ __launch_bounds__(256) void cvt_z_kernel(const float* __restrict__ z,
                                                    unsigned short* __restrict__ zh,
                                                    unsigned short* __restrict__ zl) {
    __shared__ float T[64][65];
    const int t = threadIdx.x;
    const int hg = blockIdx.x & 15, dg = (blockIdx.x >> 4) & 3, b = blockIdx.x >> 6;
    const int c4 = (t & 15) * 4, r0 = t >> 4;
    const float* zb = z + (((size_t)(b * 256 + dg * 64)) << 10) + hg * 64;
#pragma unroll
    for (int p = 0; p < 4; ++p) {
        const int r = r0 + p * 16;
        const float4 v = *(const float4*)(zb + ((size_t)r << 10) + c4);
        T[r][c4] = v.x; T[r][c4 + 1] = v.y; T[r][c4 + 2] = v.z; T[r][c4 + 3] = v.w;
    }
    __syncthreads();
    const int tr = t >> 2, dc = (t & 3) * 16;
    const int tok = b * 1024 + hg * 64 + tr;
    unsigned short hb[16], lb[16];
#pragma unroll
    for (int j = 0; j < 16; ++j) split_f32(T[dc + j][tr], hb[j], lb[j]);
    const size_t o = (size_t)tok * 256 + dg * 64 + dc;
    ((uint4*)(zh + o))[0] = ((const uint4*)hb)[0];
    ((uint4*)(zh + o))[1] = ((const uint4*)hb)[1];
    ((uint4*)(zl + o))[0] = ((const uint4*)lb)[0];
    ((uint4*)(zl + o))[1] = ((const uint4*)lb)[1];
}

// ---- ||e_k||^2 in fp64 -> f32 ----
__global__ __launch_bounds__(256) void enorm_kernel(const float* __restrict__ emb,
                                                    float* __restrict__ enorm) {
    __shared__ double red[256];
    const int k = blockIdx.x, tid = threadIdx.x;
    const float v = emb[(size_t)k * DIMS + tid];
    red[tid] = (double)v * (double)v;
    __syncthreads();
    for (int s = 128; s; s >>= 1) {
        if (tid < s) red[tid] += red[tid + s];
        __syncthreads();
    }
    if (tid == 0) enorm[k] = (float)red[0];
}

// ---- MFMA argmin: D[code][token], block = 128 tokens x 2048-code split ----
// LDS layout (frag-order): unit (((lv*4+it)*8+kseg)*32+fm)*8 ushorts;
// DMA block bi=((lv*4+it)*4+kp) covers kseg={2kp,2kp+1}: lane l -> +l*16B. 
__global__ __launch_bounds__(256, 2) void argmin_mfma(
    const unsigned short* __restrict__ zh, const unsigned short* __restrict__ zl,
    const unsigned short* __restrict__ eh, const unsigned short* __restrict__ el,
    const float* __restrict__ enorm, float* __restrict__ pval, int* __restrict__ pidx) {
    __shared__ __align__(16) unsigned short Es[16384];
    __shared__ __align__(16) unsigned short Zs[16384];
    __shared__ float en_s[128];
    __shared__ float redv[2][128];
    __shared__ int   redi[2][128];

    const int tid = threadIdx.x;
    const int lane = tid & 63, wave = tid >> 6;
    const int mw = wave >> 1, nw = wave & 1;
    const int tile = blockIdx.x >> 2, csplit = blockIdx.x & 3;
    const int token0 = tile * 128, code0 = csplit * 2048;

    const int l31 = lane & 31, lhi = lane >> 5;
    // per-lane ushort offset within a row-group load: row (+l31)*256, dim +lhi*8
    const int lane_off = l31 * 256 + lhi * 8;

    // frag read offsets (ushort index): lane-contiguous 16B
    const int khalf = lhi, fm = l31;
    int eoff[2][2], zoff[2][2];
#pragma unroll
    for (int lv = 0; lv < 2; ++lv)
#pragma unroll
        for (int t = 0; t < 2; ++t) {
            eoff[lv][t] = (((lv * 4 + (mw * 2 + t)) * 8 + khalf) * 32 + fm) * 8;
            zoff[lv][t] = (((lv * 4 + (nw * 2 + t)) * 8 + khalf) * 32 + fm) * 8;
        }

    float bv[2] = {3.4e38f, 3.4e38f};
    int   bi[2] = {0, 0};

    f32x16 acc_h[2][2], acc_l[2][2];

    for (int ct = 0; ct < 16; ++ct) {
#pragma unroll
        for (int mt = 0; mt < 2; ++mt)
#pragma unroll
            for (int nt = 0; nt < 2; ++nt)
#pragma unroll
                for (int q = 0; q < 16; ++q) { acc_h[mt][nt][q] = 0.f; acc_l[mt][nt][q] = 0.f; }

        for (int kc = 0; kc < 4; ++kc) {
            __syncthreads();
            // async stage: wave stages it=wave for E and Z, both levels, 4 kseg-pairs
            {
                const size_t erow = (size_t)(code0 + ct * 128 + wave * 32) * 256 + kc * 64;
                const size_t zrow = (size_t)(token0 + wave * 32) * 256 + kc * 64;
#pragma unroll
                for (int lv = 0; lv < 2; ++lv) {
                    const unsigned short* eb = (lv ? el : eh) + erow + lane_off;
                    const unsigned short* zb = (lv ? zl : zh) + zrow + lane_off;
                    unsigned short* esb = &Es[((lv * 4 + wave) * 4) * 512];
                    unsigned short* zsb = &Zs[((lv * 4 + wave) * 4) * 512];
#pragma unroll
                    for (int kp = 0; kp < 4; ++kp) {
                        GLD16(eb + kp * 16, esb + kp * 512);
                        GLD16(zb + kp * 16, zsb + kp * 512);
                    }
                }
            }
            if (kc == 0 && tid < 128) en_s[tid] = enorm[code0 + ct * 128 + tid];
            __syncthreads();

#pragma unroll
            for (int ks = 0; ks < 4; ++ks) {
                const int ko = ks * 512;
                f16x8 ae[2][2], bz[2][2];
#pragma unroll
                for (int lv = 0; lv < 2; ++lv)
#pragma unroll
                    for (int t = 0; t < 2; ++t) {
                        ae[lv][t] = *(const f16x8*)(&Es[eoff[lv][t] + ko]);
                        bz[lv][t] = *(const f16x8*)(&Zs[zoff[lv][t] + ko]);
                    }
#pragma unroll
                for (int mt = 0; mt < 2; ++mt)
#pragma unroll
                    for (int nt = 0; nt < 2; ++nt) {
                        acc_h[mt][nt] = __builtin_amdgcn_mfma_f32_32x32x16_f16(ae[0][mt], bz[0][nt], acc_h[mt][nt], 0, 0, 0);
                        acc_l[mt][nt] = __builtin_amdgcn_mfma_f32_32x32x16_f16(ae[0][mt], bz[1][nt], acc_l[mt][nt], 0, 0, 0);
                        acc_l[mt][nt] = __builtin_amdgcn_mfma_f32_32x32x16_f16(ae[1][mt], bz[0][nt], acc_l[mt][nt], 0, 0, 0);
                    }
            }
        }
        // epilogue: score = ||e||^2 - 2*(hi + lo/2048); running per-lane argmin
        const int rbase = 4 * khalf;
#pragma unroll
        for (int nt = 0; nt < 2; ++nt)
#pragma unroll
            for (int mt = 0; mt < 2; ++mt)
#pragma unroll
                for (int r = 0; r < 16; ++r) {
                    const int il = mw * 64 + mt * 32 + (r & 3) + 8 * (r >> 2) + rbase;
                    const float s = en_s[il] - 2.0f * (acc_h[mt][nt][r] + acc_l[mt][nt][r] * 4.8828125e-4f);
                    const int code = code0 + ct * 128 + il;
                    if (s < bv[nt]) { bv[nt] = s; bi[nt] = code; }
                }
    }

    // combine lane-halves, then wave-halves (mw) via LDS
#pragma unroll
    for (int nt = 0; nt < 2; ++nt) {
        const float ov = __shfl_xor(bv[nt], 32);
        const int   oi = __shfl_xor(bi[nt], 32);
        if (ov < bv[nt] || (ov == bv[nt] && oi < bi[nt])) { bv[nt] = ov; bi[nt] = oi; }
        if (lane < 32) {
            const int tl = nw * 64 + nt * 32 + lane;
            redv[mw][tl] = bv[nt]; redi[mw][tl] = bi[nt];
        }
    }
    __syncthreads();
    if (tid < 128) {
        const float v0 = redv[0][tid], v1 = redv[1][tid];
        const int i0 = redi[0][tid], i1 = redi[1][tid];
        const bool t2 = (v1 < v0) || (v1 == v0 && i1 < i0);
        pval[csplit * N_TOK + token0 + tid] = t2 ? v1 : v0;
        pidx[csplit * N_TOK + token0 + tid] = t2 ? i1 : i0;
    }
}

// ---- combine 4 code-split partials ----
__global__ __launch_bounds__(256) void combine4_kernel(
    const float* __restrict__ pval, const int* __restrict__ pidx,
    int* __restrict__ idx_i, float* __restrict__ idx_f) {
    const int n = blockIdx.x * 256 + threadIdx.x;
    float bv = pval[n]; int bi = pidx[n];
#pragma unroll
    for (int s = 1; s < 4; ++s) {
        const float v = pval[s * N_TOK + n];
        const int i = pidx[s * N_TOK + n];
        if (v < bv || (v == bv && i < bi)) { bv = v; bi = i; }
    }
    idx_i[n] = bi;
    idx_f[n] = (float)bi;
}

// ---- z_q gather/transpose + loss + counts + 0.01*embed_sum into NEMA ----
__global__ __launch_bounds__(256) void gather_kernel(
    const float* __restrict__ z, const float* __restrict__ emb,
    const int* __restrict__ idx_i, float* __restrict__ out,
    float* __restrict__ loss_cell, float* __restrict__ counts,
    float* __restrict__ nema_acc) {
    const int tid = threadIdx.x;
    const int n0 = blockIdx.x * 64;
    const int b = n0 >> 10, hw0 = n0 & 1023;
    const int lane = tid & 63, w = tid >> 6;
    const int n = n0 + lane;
    const int k = idx_i[n];
    if (w == 0) atomicAdd(&counts[k], 1.0f);
    const float* zb = z + ((size_t)b << 18) + hw0 + lane;
    float* ob = out + ((size_t)b << 18) + hw0 + lane;
    float ls = 0.f;
#pragma unroll 4
    for (int d = w; d < DIMS; d += 4) {
        const float zv = zb[(size_t)d << 10];
        const float ev = emb[((size_t)k << 8) + d];
        ob[(size_t)d << 10] = ev;
        const float df = ev - zv;
        ls += df * df;
        atomicAdd(&nema_acc[((size_t)k << 8) + d], 0.01f * zv);
    }
    __shared__ float red[256];
    red[tid] = ls;
    __syncthreads();
    for (int s = 128; s; s >>= 1) {
        if (tid < s) red[tid] += red[tid + s];
        __syncthreads();
    }
    if (tid == 0) atomicAdd(loss_cell, red[0] * (0.25f / 4194304.0f));
}

// ---- cs + fp64 denom ----
__global__ __launch_bounds__(256) void cs_kernel(
    const float* __restrict__ cluster_size, const float* __restrict__ counts,
    float* __restrict__ cs, double* __restrict__ denom) {
    const int tid = threadIdx.x;
    const int k = blockIdx.x * 256 + tid;
    const float v = cluster_size[k] * 0.99f + 0.01f * counts[k] + 1e-5f;
    cs[k] = v;
    __shared__ double red[256];
    red[tid] = (double)v;
    __syncthreads();
    for (int s = 128; s; s >>= 1) {
        if (tid < s) red[tid] += red[tid + s];
        __syncthreads();
    }
    if (tid == 0) atomicAdd(denom, red[0]);
}

// ---- finalize ----
__global__ __launch_bounds__(256) void finalize_kernel(
    const float* __restrict__ ema_w, const float* __restrict__ cs,
    const double* __restrict__ denom, float* __restrict__ ncs_out,
    float* __restrict__ nema_out, float* __restrict__ nemb_out) {
    const int k = blockIdx.x, d = threadIdx.x;
    const float dn = (float)(*denom) + (float)K_CODES * 1e-5f;
    const float ncs = cs[k] / dn;
    if (d == 0) ncs_out[k] = ncs;
    const size_t off = ((size_t)k << 8) + d;
    const float ne = ema_w[off] * 0.99f + nema_out[off];
    nema_out[off] = ne;
    nemb_out[off] = ne / ncs;
}

// ---------------- launch ----------------
extern "C" void kernel_launch(void* const* d_in, const int* in_sizes, int n_in,
                              void* d_out, int out_size, void* d_ws, size_t ws_size,
                              hipStream_t stream) {
    const float* z            = (const float*)d_in[0];
    const float* emb          = (const float*)d_in[1];
    const float* cluster_size = (const float*)d_in[2];
    const float* ema_w        = (const float*)d_in[3];
    float* out = (float*)d_out;
    char*  wsb = (char*)d_ws;

    unsigned short* zh = (unsigned short*)(wsb + WS_ZH);
    unsigned short* zl = (unsigned short*)(wsb + WS_ZL);
    unsigned short* eh = (unsigned short*)(wsb + WS_EH);
    unsigned short* el = (unsigned short*)(wsb + WS_EL);
    float*  enorm  = (float*)(wsb + WS_ENORM);
    float*  pval   = (float*)(wsb + WS_PVAL);
    int*    pidx   = (int*)(wsb + WS_PIDX);
    int*    idx_i  = (int*)(wsb + WS_IDXI);
    float*  counts = (float*)(wsb + WS_COUNTS);
    float*  cs     = (float*)(wsb + WS_CS);
    double* denom  = (double*)(wsb + WS_DENOM);

    hipMemsetAsync((char*)d_out + (size_t)LOSS_OFF * 4, 0, 4, stream);
    hipMemsetAsync((char*)d_out + (size_t)NEMA_OFF * 4, 0, (size_t)2097152 * 4, stream);
    hipMemsetAsync(wsb + WS_COUNTS, 0, 32768, stream);
    hipMemsetAsync(wsb + WS_DENOM, 0, 8, stream);

    cvt_z_kernel<<<1024, 256, 0, stream>>>(z, zh, zl);
    cvt_e_kernel<<<2048, 256, 0, stream>>>(emb, eh, el);
    enorm_kernel<<<K_CODES, 256, 0, stream>>>(emb, enorm);
    argmin_mfma<<<512, 256, 0, stream>>>(zh, zl, eh, el, enorm, pval, pidx);
    combine4_kernel<<<N_TOK / 256, 256, 0, stream>>>(pval, pidx, idx_i, out + IDX_OFF);
    gather_kernel<<<N_TOK / 64, 256, 0, stream>>>(z, emb, idx_i, out + OUT_OFF,
                                                  out + LOSS_OFF, counts, out + NEMA_OFF);
    cs_kernel<<<K_CODES / 256, 256, 0, stream>>>(cluster_size, counts, cs, denom);
    finalize_kernel<<<K_CODES, 256, 0, stream>>>(ema_w, cs, denom, out + NCS_OFF,
                                                 out + NEMA_OFF, out + NEMB_OFF);
}

// Round 4
// 531.088 us; speedup vs baseline: 3.7433x; 1.6000x over previous
//
#include <hip/hip_runtime.h>

#define N_TOK   16384
#define K_CODES 8192
#define DIMS    256

// d_out offsets (floats): out, loss, idx, new_cluster_size, new_ema_w, new_embedding
#define OUT_OFF  0
#define LOSS_OFF 4194304
#define IDX_OFF  4194305
#define NCS_OFF  4210689
#define NEMA_OFF 4218881
#define NEMB_OFF 6316033

// ws byte offsets
#define WS_ZH     0u          // ushort [16384][256]  8 MB  (token-major, transposed)
#define WS_ZL     8388608u    // ushort [16384][256]  8 MB
#define WS_EH     16777216u   // ushort [8192][256]   4 MB
#define WS_EL     20971520u   // ushort [8192][256]   4 MB
#define WS_ENORM  25165824u   // f32 [8192]
#define WS_PVAL   25198592u   // f32 [4][16384]
#define WS_PIDX   25460736u   // int [4][16384]
#define WS_IDXI   25722880u   // int [16384]
#define WS_CNT    25788416u   // int [8192]
#define WS_CS     25821184u   // f32 [8192]
#define WS_OFFS   25853952u   // int [8192]
#define WS_WPOS   25886720u   // int [8192]
#define WS_TLIST  25919488u   // int [16384]
#define WS_DENOM  25985024u   // double

typedef _Float16 f16x8 __attribute__((ext_vector_type(8)));
typedef float    f32x16 __attribute__((ext_vector_type(16)));

union HU { _Float16 h; unsigned short u; };

static __device__ inline void split_f32(float x, unsigned short& hi, unsigned short& lo) {
    HU a; a.h = (_Float16)x;                    // RNE f32->f16
    float r = (x - (float)a.h) * 2048.0f;       // exact residual, scaled to normal range
    HU b; b.h = (_Float16)r;
    hi = a.u; lo = b.u;
}

static __device__ inline float join_f16(unsigned short h, unsigned short l) {
    HU a, b; a.u = h; b.u = l;
    return (float)a.h + (float)b.h * 4.8828125e-4f;
}

// async global->LDS, 16B per lane; LDS dest = wave-uniform base + lane*16
#define GLD16(gp, lp) __builtin_amdgcn_global_load_lds( \
    (const __attribute__((address_space(1))) unsigned int*)(gp), \
    (__attribute__((address_space(3))) unsigned int*)(lp), 16, 0, 0)

// ---- conversion: emb [8192][256] f32 -> eh/el (same layout) ----
__global__ __launch_bounds__(256) void cvt_e_kernel(const float* __restrict__ emb,
                                                    unsigned short* __restrict__ eh,
                                                    unsigned short* __restrict__ el) {
    const int i = blockIdx.x * 256 + threadIdx.x;   // float4 index
    const float4 v = ((const float4*)emb)[i];
    const float vv[4] = {v.x, v.y, v.z, v.w};
    ushort4 h, l;
    unsigned short* hp = &h.x; unsigned short* lp = &l.x;
#pragma unroll
    for (int j = 0; j < 4; ++j) split_f32(vv[j], hp[j], lp[j]);
    ((ushort4*)eh)[i] = h;
    ((ushort4*)el)[i] = l;
}

// ---- conversion: z [16][256][1024] f32 -> zh/zl [token][dim], LDS transpose ----
__global__ __launch_bounds__(256) void cvt_z_kernel(const float* __restrict__ z,
                                                    unsigned short* __restrict__ zh,
                                                    unsigned short* __restrict__ zl) {
    __shared__ float T[64][65];
    const int t = threadIdx.x;
    const int hg = blockIdx.x & 15, dg = (blockIdx.x >> 4) & 3, b = blockIdx.x >> 6;
    const int c4 = (t & 15) * 4, r0 = t >> 4;
    const float* zb = z + (((size_t)(b * 256 + dg * 64)) << 10) + hg * 64;
#pragma unroll
    for (int p = 0; p < 4; ++p) {
        const int r = r0 + p * 16;
        const float4 v = *(const float4*)(zb + ((size_t)r << 10) + c4);
        T[r][c4] = v.x; T[r][c4 + 1] = v.y; T[r][c4 + 2] = v.z; T[r][c4 + 3] = v.w;
    }
    __syncthreads();
    const int tr = t >> 2, dc = (t & 3) * 16;
    const int tok = b * 1024 + hg * 64 + tr;
    unsigned short hb[16], lb[16];
#pragma unroll
    for (int j = 0; j < 16; ++j) split_f32(T[dc + j][tr], hb[j], lb[j]);
    const size_t o = (size_t)tok * 256 + dg * 64 + dc;
    ((uint4*)(zh + o))[0] = ((const uint4*)hb)[0];
    ((uint4*)(zh + o))[1] = ((const uint4*)hb)[1];
    ((uint4*)(zl + o))[0] = ((const uint4*)lb)[0];
    ((uint4*)(zl + o))[1] = ((const uint4*)lb)[1];
}

// ---- ||e_k||^2 in fp64 -> f32 ----
__global__ __launch_bounds__(256) void enorm_kernel(const float* __restrict__ emb,
                                                    float* __restrict__ enorm) {
    __shared__ double red[256];
    const int k = blockIdx.x, tid = threadIdx.x;
    const float v = emb[(size_t)k * DIMS + tid];
    red[tid] = (double)v * (double)v;
    __syncthreads();
    for (int s = 128; s; s >>= 1) {
        if (tid < s) red[tid] += red[tid + s];
        __syncthreads();
    }
    if (tid == 0) enorm[k] = (float)red[0];
}

// ---- MFMA argmin: D[code][token], block = 128 tokens x 2048-code split ----
__global__ __launch_bounds__(256, 2) void argmin_mfma(
    const unsigned short* __restrict__ zh, const unsigned short* __restrict__ zl,
    const unsigned short* __restrict__ eh, const unsigned short* __restrict__ el,
    const float* __restrict__ enorm, float* __restrict__ pval, int* __restrict__ pidx) {
    __shared__ __align__(16) unsigned short Es[16384];
    __shared__ __align__(16) unsigned short Zs[16384];
    __shared__ float en_s[128];
    __shared__ float redv[2][128];
    __shared__ int   redi[2][128];

    const int tid = threadIdx.x;
    const int lane = tid & 63, wave = tid >> 6;
    const int mw = wave >> 1, nw = wave & 1;
    const int tile = blockIdx.x >> 2, csplit = blockIdx.x & 3;
    const int token0 = tile * 128, code0 = csplit * 2048;

    const int l31 = lane & 31, lhi = lane >> 5;
    const int lane_off = l31 * 256 + lhi * 8;

    const int khalf = lhi, fm = l31;
    int eoff[2][2], zoff[2][2];
#pragma unroll
    for (int lv = 0; lv < 2; ++lv)
#pragma unroll
        for (int t = 0; t < 2; ++t) {
            eoff[lv][t] = (((lv * 4 + (mw * 2 + t)) * 8 + khalf) * 32 + fm) * 8;
            zoff[lv][t] = (((lv * 4 + (nw * 2 + t)) * 8 + khalf) * 32 + fm) * 8;
        }

    float bv[2] = {3.4e38f, 3.4e38f};
    int   bi[2] = {0, 0};

    f32x16 acc_h[2][2], acc_l[2][2];

    for (int ct = 0; ct < 16; ++ct) {
#pragma unroll
        for (int mt = 0; mt < 2; ++mt)
#pragma unroll
            for (int nt = 0; nt < 2; ++nt)
#pragma unroll
                for (int q = 0; q < 16; ++q) { acc_h[mt][nt][q] = 0.f; acc_l[mt][nt][q] = 0.f; }

        for (int kc = 0; kc < 4; ++kc) {
            __syncthreads();
            {
                const size_t erow = (size_t)(code0 + ct * 128 + wave * 32) * 256 + kc * 64;
                const size_t zrow = (size_t)(token0 + wave * 32) * 256 + kc * 64;
#pragma unroll
                for (int lv = 0; lv < 2; ++lv) {
                    const unsigned short* eb = (lv ? el : eh) + erow + lane_off;
                    const unsigned short* zb = (lv ? zl : zh) + zrow + lane_off;
                    unsigned short* esb = &Es[((lv * 4 + wave) * 4) * 512];
                    unsigned short* zsb = &Zs[((lv * 4 + wave) * 4) * 512];
#pragma unroll
                    for (int kp = 0; kp < 4; ++kp) {
                        GLD16(eb + kp * 16, esb + kp * 512);
                        GLD16(zb + kp * 16, zsb + kp * 512);
                    }
                }
            }
            if (kc == 0 && tid < 128) en_s[tid] = enorm[code0 + ct * 128 + tid];
            __syncthreads();

#pragma unroll
            for (int ks = 0; ks < 4; ++ks) {
                const int ko = ks * 512;
                f16x8 ae[2][2], bz[2][2];
#pragma unroll
                for (int lv = 0; lv < 2; ++lv)
#pragma unroll
                    for (int t = 0; t < 2; ++t) {
                        ae[lv][t] = *(const f16x8*)(&Es[eoff[lv][t] + ko]);
                        bz[lv][t] = *(const f16x8*)(&Zs[zoff[lv][t] + ko]);
                    }
#pragma unroll
                for (int mt = 0; mt < 2; ++mt)
#pragma unroll
                    for (int nt = 0; nt < 2; ++nt) {
                        acc_h[mt][nt] = __builtin_amdgcn_mfma_f32_32x32x16_f16(ae[0][mt], bz[0][nt], acc_h[mt][nt], 0, 0, 0);
                        acc_l[mt][nt] = __builtin_amdgcn_mfma_f32_32x32x16_f16(ae[0][mt], bz[1][nt], acc_l[mt][nt], 0, 0, 0);
                        acc_l[mt][nt] = __builtin_amdgcn_mfma_f32_32x32x16_f16(ae[1][mt], bz[0][nt], acc_l[mt][nt], 0, 0, 0);
                    }
            }
        }
        const int rbase = 4 * khalf;
#pragma unroll
        for (int nt = 0; nt < 2; ++nt)
#pragma unroll
            for (int mt = 0; mt < 2; ++mt)
#pragma unroll
                for (int r = 0; r < 16; ++r) {
                    const int il = mw * 64 + mt * 32 + (r & 3) + 8 * (r >> 2) + rbase;
                    const float s = en_s[il] - 2.0f * (acc_h[mt][nt][r] + acc_l[mt][nt][r] * 4.8828125e-4f);
                    const int code = code0 + ct * 128 + il;
                    if (s < bv[nt]) { bv[nt] = s; bi[nt] = code; }
                }
    }

#pragma unroll
    for (int nt = 0; nt < 2; ++nt) {
        const float ov = __shfl_xor(bv[nt], 32);
        const int   oi = __shfl_xor(bi[nt], 32);
        if (ov < bv[nt] || (ov == bv[nt] && oi < bi[nt])) { bv[nt] = ov; bi[nt] = oi; }
        if (lane < 32) {
            const int tl = nw * 64 + nt * 32 + lane;
            redv[mw][tl] = bv[nt]; redi[mw][tl] = bi[nt];
        }
    }
    __syncthreads();
    if (tid < 128) {
        const float v0 = redv[0][tid], v1 = redv[1][tid];
        const int i0 = redi[0][tid], i1 = redi[1][tid];
        const bool t2 = (v1 < v0) || (v1 == v0 && i1 < i0);
        pval[csplit * N_TOK + token0 + tid] = t2 ? v1 : v0;
        pidx[csplit * N_TOK + token0 + tid] = t2 ? i1 : i0;
    }
}

// ---- combine 4 code-split partials + per-code int counts ----
__global__ __launch_bounds__(256) void combine4_kernel(
    const float* __restrict__ pval, const int* __restrict__ pidx,
    int* __restrict__ idx_i, float* __restrict__ idx_f, int* __restrict__ cnt) {
    const int n = blockIdx.x * 256 + threadIdx.x;
    float bv = pval[n]; int bi = pidx[n];
#pragma unroll
    for (int s = 1; s < 4; ++s) {
        const float v = pval[s * N_TOK + n];
        const int i = pidx[s * N_TOK + n];
        if (v < bv || (v == bv && i < bi)) { bv = v; bi = i; }
    }
    idx_i[n] = bi;
    idx_f[n] = (float)bi;
    atomicAdd(&cnt[bi], 1);
}

// ---- exclusive scan of 8192 counts (single block) ----
__global__ __launch_bounds__(256) void scan_kernel(const int* __restrict__ cnt,
                                                   int* __restrict__ offs,
                                                   int* __restrict__ wpos) {
    __shared__ int part[256];
    const int tid = threadIdx.x;
    const int base = tid * 32;
    int loc[32];
    int s = 0;
#pragma unroll
    for (int j = 0; j < 32; ++j) { loc[j] = cnt[base + j]; s += loc[j]; }
    part[tid] = s;
    __syncthreads();
    for (int off = 1; off < 256; off <<= 1) {
        int v = 0;
        if (tid >= off) v = part[tid - off];
        __syncthreads();
        if (tid >= off) part[tid] += v;
        __syncthreads();
    }
    int run = (tid > 0) ? part[tid - 1] : 0;
#pragma unroll
    for (int j = 0; j < 32; ++j) {
        offs[base + j] = run;
        wpos[base + j] = run;
        run += loc[j];
    }
}

// ---- scatter token ids into per-code segments ----
__global__ __launch_bounds__(256) void scatter_kernel(const int* __restrict__ idx_i,
                                                      int* __restrict__ wpos,
                                                      int* __restrict__ tlist) {
    const int n = blockIdx.x * 256 + threadIdx.x;
    const int k = idx_i[n];
    const int pos = atomicAdd(&wpos[k], 1);
    tlist[pos] = n;
}

// ---- cs + fp64 denom ----
__global__ __launch_bounds__(256) void cs_kernel(
    const float* __restrict__ cluster_size, const int* __restrict__ cnt,
    float* __restrict__ cs, double* __restrict__ denom) {
    const int tid = threadIdx.x;
    const int k = blockIdx.x * 256 + tid;
    const float v = cluster_size[k] * 0.99f + 0.01f * (float)cnt[k] + 1e-5f;
    cs[k] = v;
    __shared__ double red[256];
    red[tid] = (double)v;
    __syncthreads();
    for (int s = 128; s; s >>= 1) {
        if (tid < s) red[tid] += red[tid + s];
        __syncthreads();
    }
    if (tid == 0) atomicAdd(denom, red[0]);
}

// ---- per-code embed_sum (from token-major zh/zl) + finalize ----
__global__ __launch_bounds__(256) void nema_finalize(
    const unsigned short* __restrict__ zh, const unsigned short* __restrict__ zl,
    const int* __restrict__ offs, const int* __restrict__ cnt,
    const int* __restrict__ tlist, const float* __restrict__ ema_w,
    const float* __restrict__ cs, const double* __restrict__ denom,
    float* __restrict__ ncs_out, float* __restrict__ nema_out,
    float* __restrict__ nemb_out) {
    const int k = blockIdx.x, d = threadIdx.x;
    const int beg = offs[k], c = cnt[k];
    float acc = 0.f;
    for (int i = 0; i < c; ++i) {
        const int tok = tlist[beg + i];
        const size_t o = ((size_t)tok << 8) + d;
        acc += join_f16(zh[o], zl[o]);
    }
    const float dn = (float)(*denom) + (float)K_CODES * 1e-5f;
    const float ncs = cs[k] / dn;
    if (d == 0) ncs_out[k] = ncs;
    const size_t off = ((size_t)k << 8) + d;
    const float ne = ema_w[off] * 0.99f + 0.01f * acc;
    nema_out[off] = ne;
    nemb_out[off] = ne / ncs;
}

// ---- z_q gather/transpose + loss (no atomics except 1 loss add/block) ----
// grid: 1024 = 256 token-groups x 4 dim-groups
__global__ __launch_bounds__(256) void gather_out(
    const float* __restrict__ z, const float* __restrict__ emb,
    const int* __restrict__ idx_i, float* __restrict__ out,
    float* __restrict__ loss_cell) {
    const int tid = threadIdx.x;
    const int n0 = (blockIdx.x >> 2) * 64;
    const int dg = (blockIdx.x & 3) * 64;
    const int b = n0 >> 10, hw0 = n0 & 1023;
    const int lane = tid & 63, w = tid >> 6;
    const int n = n0 + lane;
    const int k = idx_i[n];
    const float* zb = z + ((size_t)b << 18) + hw0 + lane;
    float* ob = out + ((size_t)b << 18) + hw0 + lane;
    float ls = 0.f;
#pragma unroll 4
    for (int d = dg + w; d < dg + 64; d += 4) {
        const float zv = zb[(size_t)d << 10];
        const float ev = emb[((size_t)k << 8) + d];
        ob[(size_t)d << 10] = ev;
        const float df = ev - zv;
        ls += df * df;
    }
    __shared__ float red[256];
    red[tid] = ls;
    __syncthreads();
    for (int s = 128; s; s >>= 1) {
        if (tid < s) red[tid] += red[tid + s];
        __syncthreads();
    }
    if (tid == 0) atomicAdd(loss_cell, red[0] * (0.25f / 4194304.0f));
}

// ---------------- launch ----------------
extern "C" void kernel_launch(void* const* d_in, const int* in_sizes, int n_in,
                              void* d_out, int out_size, void* d_ws, size_t ws_size,
                              hipStream_t stream) {
    const float* z            = (const float*)d_in[0];
    const float* emb          = (const float*)d_in[1];
    const float* cluster_size = (const float*)d_in[2];
    const float* ema_w        = (const float*)d_in[3];
    float* out = (float*)d_out;
    char*  wsb = (char*)d_ws;

    unsigned short* zh = (unsigned short*)(wsb + WS_ZH);
    unsigned short* zl = (unsigned short*)(wsb + WS_ZL);
    unsigned short* eh = (unsigned short*)(wsb + WS_EH);
    unsigned short* el = (unsigned short*)(wsb + WS_EL);
    float*  enorm  = (float*)(wsb + WS_ENORM);
    float*  pval   = (float*)(wsb + WS_PVAL);
    int*    pidx   = (int*)(wsb + WS_PIDX);
    int*    idx_i  = (int*)(wsb + WS_IDXI);
    int*    cnt    = (int*)(wsb + WS_CNT);
    float*  cs     = (float*)(wsb + WS_CS);
    int*    offs   = (int*)(wsb + WS_OFFS);
    int*    wpos   = (int*)(wsb + WS_WPOS);
    int*    tlist  = (int*)(wsb + WS_TLIST);
    double* denom  = (double*)(wsb + WS_DENOM);

    hipMemsetAsync((char*)d_out + (size_t)LOSS_OFF * 4, 0, 4, stream);
    hipMemsetAsync(wsb + WS_CNT, 0, 32768, stream);
    hipMemsetAsync(wsb + WS_DENOM, 0, 8, stream);

    cvt_z_kernel<<<1024, 256, 0, stream>>>(z, zh, zl);
    cvt_e_kernel<<<2048, 256, 0, stream>>>(emb, eh, el);
    enorm_kernel<<<K_CODES, 256, 0, stream>>>(emb, enorm);
    argmin_mfma<<<512, 256, 0, stream>>>(zh, zl, eh, el, enorm, pval, pidx);
    combine4_kernel<<<N_TOK / 256, 256, 0, stream>>>(pval, pidx, idx_i,
                                                     out + IDX_OFF, cnt);
    scan_kernel<<<1, 256, 0, stream>>>(cnt, offs, wpos);
    scatter_kernel<<<N_TOK / 256, 256, 0, stream>>>(idx_i, wpos, tlist);
    cs_kernel<<<K_CODES / 256, 256, 0, stream>>>(cluster_size, cnt, cs, denom);
    nema_finalize<<<K_CODES, 256, 0, stream>>>(zh, zl, offs, cnt, tlist, ema_w,
                                               cs, denom, out + NCS_OFF,
                                               out + NEMA_OFF, out + NEMB_OFF);
    gather_out<<<1024, 256, 0, stream>>>(z, emb, idx_i, out + OUT_OFF,
                                         out + LOSS_OFF);
}

// Round 5
// 471.093 us; speedup vs baseline: 4.2200x; 1.1274x over previous
//
#include <hip/hip_runtime.h>

#define N_TOK   16384
#define K_CODES 8192
#define DIMS    256

// d_out offsets (floats): out, loss, idx, new_cluster_size, new_ema_w, new_embedding
#define OUT_OFF  0
#define LOSS_OFF 4194304
#define IDX_OFF  4194305
#define NCS_OFF  4210689
#define NEMA_OFF 4218881
#define NEMB_OFF 6316033

// ws byte offsets
#define WS_ZH     0u          // ushort [16384][256]  8 MB  (token-major, transposed)
#define WS_ZL     8388608u    // ushort [16384][256]  8 MB
#define WS_EH     16777216u   // ushort [8192][256]   4 MB
#define WS_EL     20971520u   // ushort [8192][256]   4 MB
#define WS_ENORM  25165824u   // f32 [8192]
#define WS_PVAL   25198592u   // f32 [4][16384]
#define WS_PIDX   25460736u   // int [4][16384]
#define WS_IDXI   25722880u   // int [16384]
#define WS_CNT    25788416u   // int [8192]
#define WS_CS     25821184u   // f32 [8192]
#define WS_OFFS   25853952u   // int [8192]
#define WS_WPOS   25886720u   // int [8192]
#define WS_TLIST  25919488u   // int [16384]
#define WS_DENOM  25985024u   // double

typedef _Float16 f16x8 __attribute__((ext_vector_type(8)));
typedef float    f32x16 __attribute__((ext_vector_type(16)));

union HU { _Float16 h; unsigned short u; };

static __device__ inline void split_f32(float x, unsigned short& hi, unsigned short& lo) {
    HU a; a.h = (_Float16)x;                    // RNE f32->f16
    float r = (x - (float)a.h) * 2048.0f;       // exact residual, scaled to normal range
    HU b; b.h = (_Float16)r;
    hi = a.u; lo = b.u;
}

static __device__ inline float join_f16(unsigned short h, unsigned short l) {
    HU a, b; a.u = h; b.u = l;
    return (float)a.h + (float)b.h * 4.8828125e-4f;
}

// async global->LDS, 16B per lane; LDS dest = wave-uniform base + lane*16
#define GLD16(gp, lp) __builtin_amdgcn_global_load_lds( \
    (const __attribute__((address_space(1))) unsigned int*)(gp), \
    (__attribute__((address_space(3))) unsigned int*)(lp), 16, 0, 0)

// ---- conversion: emb [8192][256] f32 -> eh/el (same layout) ----
__global__ __launch_bounds__(256) void cvt_e_kernel(const float* __restrict__ emb,
                                                    unsigned short* __restrict__ eh,
                                                    unsigned short* __restrict__ el) {
    const int i = blockIdx.x * 256 + threadIdx.x;   // float4 index
    const float4 v = ((const float4*)emb)[i];
    const float vv[4] = {v.x, v.y, v.z, v.w};
    ushort4 h, l;
    unsigned short* hp = &h.x; unsigned short* lp = &l.x;
#pragma unroll
    for (int j = 0; j < 4; ++j) split_f32(vv[j], hp[j], lp[j]);
    ((ushort4*)eh)[i] = h;
    ((ushort4*)el)[i] = l;
}

// ---- conversion: z [16][256][1024] f32 -> zh/zl [token][dim], LDS transpose ----
__global__ __launch_bounds__(256) void cvt_z_kernel(const float* __restrict__ z,
                                                    unsigned short* __restrict__ zh,
                                                    unsigned short* __restrict__ zl) {
    __shared__ float T[64][65];
    const int t = threadIdx.x;
    const int hg = blockIdx.x & 15, dg = (blockIdx.x >> 4) & 3, b = blockIdx.x >> 6;
    const int c4 = (t & 15) * 4, r0 = t >> 4;
    const float* zb = z + (((size_t)(b * 256 + dg * 64)) << 10) + hg * 64;
#pragma unroll
    for (int p = 0; p < 4; ++p) {
        const int r = r0 + p * 16;
        const float4 v = *(const float4*)(zb + ((size_t)r << 10) + c4);
        T[r][c4] = v.x; T[r][c4 + 1] = v.y; T[r][c4 + 2] = v.z; T[r][c4 + 3] = v.w;
    }
    __syncthreads();
    const int tr = t >> 2, dc = (t & 3) * 16;
    const int tok = b * 1024 + hg * 64 + tr;
    unsigned short hb[16], lb[16];
#pragma unroll
    for (int j = 0; j < 16; ++j) split_f32(T[dc + j][tr], hb[j], lb[j]);
    const size_t o = (size_t)tok * 256 + dg * 64 + dc;
    ((uint4*)(zh + o))[0] = ((const uint4*)hb)[0];
    ((uint4*)(zh + o))[1] = ((const uint4*)hb)[1];
    ((uint4*)(zl + o))[0] = ((const uint4*)lb)[0];
    ((uint4*)(zl + o))[1] = ((const uint4*)lb)[1];
}

// ---- ||e_k||^2 in fp64 -> f32 ----
__global__ __launch_bounds__(256) void enorm_kernel(const float* __restrict__ emb,
                                                    float* __restrict__ enorm) {
    __shared__ double red[256];
    const int k = blockIdx.x, tid = threadIdx.x;
    const float v = emb[(size_t)k * DIMS + tid];
    red[tid] = (double)v * (double)v;
    __syncthreads();
    for (int s = 128; s; s >>= 1) {
        if (tid < s) red[tid] += red[tid + s];
        __syncthreads();
    }
    if (tid == 0) enorm[k] = (float)red[0];
}

// ---- MFMA argmin v3: 64-token tile, Z K-resident in registers ----
// grid: 256 token-tiles x 4 code-splits = 1024 blocks.
// Z frags (K=256, 2 levels) live in 128 VGPRs; E streams via 2x32KB LDS ping-pong.
__global__ __launch_bounds__(256, 2) void argmin_mfma(
    const unsigned short* __restrict__ zh, const unsigned short* __restrict__ zl,
    const unsigned short* __restrict__ eh, const unsigned short* __restrict__ el,
    const float* __restrict__ enorm, float* __restrict__ pval, int* __restrict__ pidx) {
    __shared__ __align__(16) unsigned short S[32768];   // 64 KB: Z staging, then E ping-pong
    __shared__ float en_s[2][128];
    __shared__ float redv[2][64];
    __shared__ int   redi[2][64];

    const int tid = threadIdx.x;
    const int lane = tid & 63, wave = tid >> 6;
    const int mw = wave >> 1, nw = wave & 1;     // mw: code 64-half, nw: token 32-half
    const int tile = blockIdx.x >> 2, csplit = blockIdx.x & 3;
    const int token0 = tile * 64, code0 = csplit * 2048;

    const int l31 = lane & 31, lhi = lane >> 5;
    const int lane_off = l31 * 256 + lhi * 8;    // global: row l31, dim-sub lhi*8

    // ---- phase 1: stage Z (frag order) and read register-resident frags ----
    {
        const int lv = wave >> 1, nh = wave & 1;
        const unsigned short* zb = (lv ? zl : zh) +
            (size_t)(token0 + nh * 32) * 256 + lane_off;
        unsigned short* sb = &S[((lv * 2 + nh) * 16) * 512];
#pragma unroll
        for (int ks = 0; ks < 16; ++ks) GLD16(zb + ks * 16, sb + ks * 512);
    }
    __syncthreads();
    f16x8 Zr[2][16];
#pragma unroll
    for (int lv = 0; lv < 2; ++lv)
#pragma unroll
        for (int ks = 0; ks < 16; ++ks)
            Zr[lv][ks] = *(const f16x8*)&S[(((lv * 2 + nw) * 16) + ks) * 512 + lane * 8];
    __syncthreads();

    // E base pointers (lane offset folded in); chunk (ct,kc): + ct*32768 + kc*64
    const unsigned short* ebase[2] = {
        eh + (size_t)(code0 + wave * 32) * 256 + lane_off,
        el + (size_t)(code0 + wave * 32) * 256 + lane_off };

    // prologue: stage chunk (0,0) into buf0 + en_s[0]
#pragma unroll
    for (int lv = 0; lv < 2; ++lv) {
        unsigned short* sb = &S[((lv * 4 + wave) * 4) * 512];
#pragma unroll
        for (int ksl = 0; ksl < 4; ++ksl) GLD16(ebase[lv] + ksl * 16, sb + ksl * 512);
    }
    if (tid < 128) en_s[0][tid] = enorm[code0 + tid];
    __syncthreads();

    float bv = 3.4e38f;
    int   bi = 0;

    for (int ct = 0; ct < 16; ++ct) {
        f32x16 acc_h[2], acc_l[2];
#pragma unroll
        for (int mt = 0; mt < 2; ++mt)
#pragma unroll
            for (int q = 0; q < 16; ++q) { acc_h[mt][q] = 0.f; acc_l[mt][q] = 0.f; }

#pragma unroll
        for (int kc = 0; kc < 4; ++kc) {
            const int p = kc & 1, np = (kc + 1) & 1;
            // stage next chunk (async, overlaps compute below)
            if (!(ct == 15 && kc == 3)) {
                const int nct = (kc == 3) ? ct + 1 : ct;
                const int nkc = (kc + 1) & 3;
#pragma unroll
                for (int lv = 0; lv < 2; ++lv) {
                    const unsigned short* eb = ebase[lv] + nct * 32768 + nkc * 64;
                    unsigned short* sb = &S[np * 16384 + ((lv * 4 + wave) * 4) * 512];
#pragma unroll
                    for (int ksl = 0; ksl < 4; ++ksl) GLD16(eb + ksl * 16, sb + ksl * 512);
                }
            }
            if (kc == 0 && ct < 15 && tid < 128)
                en_s[(ct + 1) & 1][tid] = enorm[code0 + (ct + 1) * 128 + tid];

            // compute current chunk from buf p
#pragma unroll
            for (int ksl = 0; ksl < 4; ++ksl) {
                const int ksg = kc * 4 + ksl;
                f16x8 ae[2][2];
#pragma unroll
                for (int lv = 0; lv < 2; ++lv)
#pragma unroll
                    for (int mt = 0; mt < 2; ++mt)
                        ae[lv][mt] = *(const f16x8*)&S[p * 16384 +
                            ((lv * 4 + (mw * 2 + mt)) * 4 + ksl) * 512 + lane * 8];
#pragma unroll
                for (int mt = 0; mt < 2; ++mt) {
                    acc_h[mt] = __builtin_amdgcn_mfma_f32_32x32x16_f16(ae[0][mt], Zr[0][ksg], acc_h[mt], 0, 0, 0);
                    acc_l[mt] = __builtin_amdgcn_mfma_f32_32x32x16_f16(ae[0][mt], Zr[1][ksg], acc_l[mt], 0, 0, 0);
                    acc_l[mt] = __builtin_amdgcn_mfma_f32_32x32x16_f16(ae[1][mt], Zr[0][ksg], acc_l[mt], 0, 0, 0);
                }
            }

            if (kc == 3) {
                // epilogue: score = ||e||^2 - 2*(hi + lo/2048); per-lane argmin
                const int rbase = 4 * lhi;
#pragma unroll
                for (int mt = 0; mt < 2; ++mt)
#pragma unroll
                    for (int r = 0; r < 16; ++r) {
                        const int il = mw * 64 + mt * 32 + (r & 3) + 8 * (r >> 2) + rbase;
                        const float s = en_s[ct & 1][il] -
                            2.0f * (acc_h[mt][r] + acc_l[mt][r] * 4.8828125e-4f);
                        const int code = code0 + ct * 128 + il;
                        if (s < bv) { bv = s; bi = code; }
                    }
            }
            __syncthreads();
        }
    }

    // combine lane-halves (same token, different codes), then mw waves via LDS
    {
        const float ov = __shfl_xor(bv, 32);
        const int   oi = __shfl_xor(bi, 32);
        if (ov < bv || (ov == bv && oi < bi)) { bv = ov; bi = oi; }
        if (lane < 32) {
            redv[mw][nw * 32 + lane] = bv;
            redi[mw][nw * 32 + lane] = bi;
        }
    }
    __syncthreads();
    if (tid < 64) {
        const float v0 = redv[0][tid], v1 = redv[1][tid];
        const int i0 = redi[0][tid], i1 = redi[1][tid];
        const bool t2 = (v1 < v0) || (v1 == v0 && i1 < i0);
        pval[csplit * N_TOK + token0 + tid] = t2 ? v1 : v0;
        pidx[csplit * N_TOK + token0 + tid] = t2 ? i1 : i0;
    }
}

// ---- combine 4 code-split partials + per-code int counts ----
__global__ __launch_bounds__(256) void combine4_kernel(
    const float* __restrict__ pval, const int* __restrict__ pidx,
    int* __restrict__ idx_i, float* __restrict__ idx_f, int* __restrict__ cnt) {
    const int n = blockIdx.x * 256 + threadIdx.x;
    float bv = pval[n]; int bi = pidx[n];
#pragma unroll
    for (int s = 1; s < 4; ++s) {
        const float v = pval[s * N_TOK + n];
        const int i = pidx[s * N_TOK + n];
        if (v < bv || (v == bv && i < bi)) { bv = v; bi = i; }
    }
    idx_i[n] = bi;
    idx_f[n] = (float)bi;
    atomicAdd(&cnt[bi], 1);
}

// ---- exclusive scan of 8192 counts (single block) ----
__global__ __launch_bounds__(256) void scan_kernel(const int* __restrict__ cnt,
                                                   int* __restrict__ offs,
                                                   int* __restrict__ wpos) {
    __shared__ int part[256];
    const int tid = threadIdx.x;
    const int base = tid * 32;
    int loc[32];
    int s = 0;
#pragma unroll
    for (int j = 0; j < 32; ++j) { loc[j] = cnt[base + j]; s += loc[j]; }
    part[tid] = s;
    __syncthreads();
    for (int off = 1; off < 256; off <<= 1) {
        int v = 0;
        if (tid >= off) v = part[tid - off];
        __syncthreads();
        if (tid >= off) part[tid] += v;
        __syncthreads();
    }
    int run = (tid > 0) ? part[tid - 1] : 0;
#pragma unroll
    for (int j = 0; j < 32; ++j) {
        offs[base + j] = run;
        wpos[base + j] = run;
        run += loc[j];
    }
}

// ---- scatter token ids into per-code segments ----
__global__ __launch_bounds__(256) void scatter_kernel(const int* __restrict__ idx_i,
                                                      int* __restrict__ wpos,
                                                      int* __restrict__ tlist) {
    const int n = blockIdx.x * 256 + threadIdx.x;
    const int k = idx_i[n];
    const int pos = atomicAdd(&wpos[k], 1);
    tlist[pos] = n;
}

// ---- cs + fp64 denom ----
__global__ __launch_bounds__(256) void cs_kernel(
    const float* __restrict__ cluster_size, const int* __restrict__ cnt,
    float* __restrict__ cs, double* __restrict__ denom) {
    const int tid = threadIdx.x;
    const int k = blockIdx.x * 256 + tid;
    const float v = cluster_size[k] * 0.99f + 0.01f * (float)cnt[k] + 1e-5f;
    cs[k] = v;
    __shared__ double red[256];
    red[tid] = (double)v;
    __syncthreads();
    for (int s = 128; s; s >>= 1) {
        if (tid < s) red[tid] += red[tid + s];
        __syncthreads();
    }
    if (tid == 0) atomicAdd(denom, red[0]);
}

// ---- per-code embed_sum (from token-major zh/zl) + finalize ----
__global__ __launch_bounds__(256) void nema_finalize(
    const unsigned short* __restrict__ zh, const unsigned short* __restrict__ zl,
    const int* __restrict__ offs, const int* __restrict__ cnt,
    const int* __restrict__ tlist, const float* __restrict__ ema_w,
    const float* __restrict__ cs, const double* __restrict__ denom,
    float* __restrict__ ncs_out, float* __restrict__ nema_out,
    float* __restrict__ nemb_out) {
    const int k = blockIdx.x, d = threadIdx.x;
    const int beg = offs[k], c = cnt[k];
    float acc = 0.f;
    for (int i = 0; i < c; ++i) {
        const int tok = tlist[beg + i];
        const size_t o = ((size_t)tok << 8) + d;
        acc += join_f16(zh[o], zl[o]);
    }
    const float dn = (float)(*denom) + (float)K_CODES * 1e-5f;
    const float ncs = cs[k] / dn;
    if (d == 0) ncs_out[k] = ncs;
    const size_t off = ((size_t)k << 8) + d;
    const float ne = ema_w[off] * 0.99f + 0.01f * acc;
    nema_out[off] = ne;
    nemb_out[off] = ne / ncs;
}

// ---- z_q gather/transpose + loss ----
__global__ __launch_bounds__(256) void gather_out(
    const float* __restrict__ z, const float* __restrict__ emb,
    const int* __restrict__ idx_i, float* __restrict__ out,
    float* __restrict__ loss_cell) {
    const int tid = threadIdx.x;
    const int n0 = (blockIdx.x >> 2) * 64;
    const int dg = (blockIdx.x & 3) * 64;
    const int b = n0 >> 10, hw0 = n0 & 1023;
    const int lane = tid & 63, w = tid >> 6;
    const int n = n0 + lane;
    const int k = idx_i[n];
    const float* zb = z + ((size_t)b << 18) + hw0 + lane;
    float* ob = out + ((size_t)b << 18) + hw0 + lane;
    float ls = 0.f;
#pragma unroll 4
    for (int d = dg + w; d < dg + 64; d += 4) {
        const float zv = zb[(size_t)d << 10];
        const float ev = emb[((size_t)k << 8) + d];
        ob[(size_t)d << 10] = ev;
        const float df = ev - zv;
        ls += df * df;
    }
    __shared__ float red[256];
    red[tid] = ls;
    __syncthreads();
    for (int s = 128; s; s >>= 1) {
        if (tid < s) red[tid] += red[tid + s];
        __syncthreads();
    }
    if (tid == 0) atomicAdd(loss_cell, red[0] * (0.25f / 4194304.0f));
}

// ---------------- launch ----------------
extern "C" void kernel_launch(void* const* d_in, const int* in_sizes, int n_in,
                              void* d_out, int out_size, void* d_ws, size_t ws_size,
                              hipStream_t stream) {
    const float* z            = (const float*)d_in[0];
    const float* emb          = (const float*)d_in[1];
    const float* cluster_size = (const float*)d_in[2];
    const float* ema_w        = (const float*)d_in[3];
    float* out = (float*)d_out;
    char*  wsb = (char*)d_ws;

    unsigned short* zh = (unsigned short*)(wsb + WS_ZH);
    unsigned short* zl = (unsigned short*)(wsb + WS_ZL);
    unsigned short* eh = (unsigned short*)(wsb + WS_EH);
    unsigned short* el = (unsigned short*)(wsb + WS_EL);
    float*  enorm  = (float*)(wsb + WS_ENORM);
    float*  pval   = (float*)(wsb + WS_PVAL);
    int*    pidx   = (int*)(wsb + WS_PIDX);
    int*    idx_i  = (int*)(wsb + WS_IDXI);
    int*    cnt    = (int*)(wsb + WS_CNT);
    float*  cs     = (float*)(wsb + WS_CS);
    int*    offs   = (int*)(wsb + WS_OFFS);
    int*    wpos   = (int*)(wsb + WS_WPOS);
    int*    tlist  = (int*)(wsb + WS_TLIST);
    double* denom  = (double*)(wsb + WS_DENOM);

    hipMemsetAsync((char*)d_out + (size_t)LOSS_OFF * 4, 0, 4, stream);
    hipMemsetAsync(wsb + WS_CNT, 0, 32768, stream);
    hipMemsetAsync(wsb + WS_DENOM, 0, 8, stream);

    cvt_z_kernel<<<1024, 256, 0, stream>>>(z, zh, zl);
    cvt_e_kernel<<<2048, 256, 0, stream>>>(emb, eh, el);
    enorm_kernel<<<K_CODES, 256, 0, stream>>>(emb, enorm);
    argmin_mfma<<<1024, 256, 0, stream>>>(zh, zl, eh, el, enorm, pval, pidx);
    combine4_kernel<<<N_TOK / 256, 256, 0, stream>>>(pval, pidx, idx_i,
                                                     out + IDX_OFF, cnt);
    scan_kernel<<<1, 256, 0, stream>>>(cnt, offs, wpos);
    scatter_kernel<<<N_TOK / 256, 256, 0, stream>>>(idx_i, wpos, tlist);
    cs_kernel<<<K_CODES / 256, 256, 0, stream>>>(cluster_size, cnt, cs, denom);
    nema_finalize<<<K_CODES, 256, 0, stream>>>(zh, zl, offs, cnt, tlist, ema_w,
                                               cs, denom, out + NCS_OFF,
                                               out + NEMA_OFF, out + NEMB_OFF);
    gather_out<<<1024, 256, 0, stream>>>(z, emb, idx_i, out + OUT_OFF,
                                         out + LOSS_OFF);
}

// Round 6
// 418.765 us; speedup vs baseline: 4.7474x; 1.1250x over previous
//
#include <hip/hip_runtime.h>

#define N_TOK   16384
#define K_CODES 8192
#define DIMS    256

// d_out offsets (floats): out, loss, idx, new_cluster_size, new_ema_w, new_embedding
#define OUT_OFF  0
#define LOSS_OFF 4194304
#define IDX_OFF  4194305
#define NCS_OFF  4210689
#define NEMA_OFF 4218881
#define NEMB_OFF 6316033

// ws byte offsets
#define WS_ZFRAG  0u          // ushort frag-order [512 tg][2 lv][16 ks][64 lane][8] = 16 MB
#define WS_EFRAG  16777216u   // ushort frag-order [256 g][2 lv][16 ks][64 lane][8] = 8 MB
#define WS_ENORM  25165824u   // f32 [8192]
#define WS_PVAL   25198592u   // f32 [4][16384]
#define WS_PIDX   25460736u   // int [4][16384]
#define WS_IDXI   25722880u   // int [16384]
#define WS_CNT    25788416u   // int [8192]
#define WS_CS     25821184u   // f32 [8192]
#define WS_OFFS   25853952u   // int [8192]
#define WS_WPOS   25886720u   // int [8192]
#define WS_TLIST  25919488u   // int [16384]
#define WS_DENOM  25985024u   // double

typedef _Float16 f16x8 __attribute__((ext_vector_type(8)));
typedef float    f32x16 __attribute__((ext_vector_type(16)));

union HU { _Float16 h; unsigned short u; };

static __device__ inline void split_f32(float x, unsigned short& hi, unsigned short& lo) {
    HU a; a.h = (_Float16)x;                    // RNE f32->f16
    float r = (x - (float)a.h) * 2048.0f;       // exact residual, scaled to normal range
    HU b; b.h = (_Float16)r;
    hi = a.u; lo = b.u;
}

static __device__ inline float join_f16(unsigned short h, unsigned short l) {
    HU a, b; a.u = h; b.u = l;
    return (float)a.h + (float)b.h * 4.8828125e-4f;
}

// async global->LDS, 16B per lane; LDS dest = wave-uniform base + lane*16
#define GLD16(gp, lp) __builtin_amdgcn_global_load_lds( \
    (const __attribute__((address_space(1))) unsigned int*)(gp), \
    (__attribute__((address_space(3))) unsigned int*)(lp), 16, 0, 0)

// ---- z [16][256][1024] f32 -> zfrag (frag-order, 2-level split); zeroes loss/denom ----
// grid: b(16) x dg(4) x hg(16) = 1024 blocks; tile = 64 dims x 64 hw
__global__ __launch_bounds__(256) void cvt_z_kernel(const float* __restrict__ z,
                                                    unsigned short* __restrict__ zfrag,
                                                    float* __restrict__ loss_cell,
                                                    double* __restrict__ denom) {
    __shared__ float T[64][65];
    const int t = threadIdx.x;
    const int hg = blockIdx.x & 15, dg = (blockIdx.x >> 4) & 3, b = blockIdx.x >> 6;
    if (blockIdx.x == 0 && t == 0) { *loss_cell = 0.f; *denom = 0.0; }
    const int c4 = (t & 15) * 4, r0 = t >> 4;
    const float* zb = z + (((size_t)(b * 256 + dg * 64)) << 10) + hg * 64;
#pragma unroll
    for (int p = 0; p < 4; ++p) {
        const int r = r0 + p * 16;
        const float4 v = *(const float4*)(zb + ((size_t)r << 10) + c4);
        T[r][c4] = v.x; T[r][c4 + 1] = v.y; T[r][c4 + 2] = v.z; T[r][c4 + 3] = v.w;
    }
    __syncthreads();
    const int tr = t & 63, dc = (t >> 6) * 16;   // token-local tr, 16-dim chunk dc
    const int tile = b * 16 + hg;
    const int tg = tile * 2 + (tr >> 5), l31 = tr & 31;
    const int ks = dg * 4 + (dc >> 4);
    unsigned short hb[16], lb[16];
#pragma unroll
    for (int j = 0; j < 16; ++j) split_f32(T[dc + j][tr], hb[j], lb[j]);
#pragma unroll
    for (int lv = 0; lv < 2; ++lv) {
        const unsigned short* src = lv ? lb : hb;
        unsigned short* dst = zfrag + (size_t)((tg * 2 + lv) * 16 + ks) * 512;
        *(uint4*)(dst + l31 * 8)       = ((const uint4*)src)[0];   // khalf 0 (j 0..7)
        *(uint4*)(dst + 256 + l31 * 8) = ((const uint4*)src)[1];   // khalf 1 (j 8..15)
    }
}

// ---- emb -> efrag (frag-order split) + ||e||^2 (f64) + cnt zero. grid: 256 blocks ----
__global__ __launch_bounds__(256) void cvt_e_enorm(const float* __restrict__ emb,
                                                   unsigned short* __restrict__ efrag,
                                                   float* __restrict__ enorm,
                                                   int* __restrict__ cnt) {
    __shared__ double red[256];
    const int t = threadIdx.x, g = blockIdx.x;
    const int lane = t & 63, q = t >> 6;
    const int l31 = lane & 31, lhi = lane >> 5;
    if (g < 32) cnt[g * 256 + t] = 0;
    const float* rowp = emb + (size_t)(g * 32 + l31) * 256 + lhi * 8;
    double s = 0.0;
#pragma unroll
    for (int kk = 0; kk < 4; ++kk) {
        const int ks = q * 4 + kk;
        const float4 a = *(const float4*)(rowp + ks * 16);
        const float4 bq = *(const float4*)(rowp + ks * 16 + 4);
        const float vv[8] = {a.x, a.y, a.z, a.w, bq.x, bq.y, bq.z, bq.w};
        unsigned short hb[8], lb[8];
#pragma unroll
        for (int j = 0; j < 8; ++j) {
            split_f32(vv[j], hb[j], lb[j]);
            s += (double)vv[j] * (double)vv[j];
        }
        *(uint4*)(efrag + (size_t)((g * 2 + 0) * 16 + ks) * 512 + lane * 8) = *(const uint4*)hb;
        *(uint4*)(efrag + (size_t)((g * 2 + 1) * 16 + ks) * 512 + lane * 8) = *(const uint4*)lb;
    }
    red[t] = s;
    __syncthreads();
    if (t < 32) {
        double acc = 0.0;
#pragma unroll
        for (int qq = 0; qq < 4; ++qq) acc += red[qq * 64 + t] + red[qq * 64 + 32 + t];
        enorm[g * 32 + t] = (float)acc;
    }
}

// ---- MFMA argmin v4: block = 128 tokens (4 waves x 32) x 64-code chunks ----
// All waves share the staged 64 codes; Z register-resident; E 2x16KB ping-pong.
__global__ __launch_bounds__(256, 2) void argmin_mfma(
    const unsigned short* __restrict__ zfrag, const unsigned short* __restrict__ efrag,
    const float* __restrict__ enorm, float* __restrict__ pval, int* __restrict__ pidx) {
    __shared__ __align__(16) unsigned short E[2][8192];   // [buf][slot(lv*2+cg)*4+ksl][lane*8]
    __shared__ float en_s[2][64];

    const int tid = threadIdx.x, lane = tid & 63, wave = tid >> 6;
    const int tile = blockIdx.x & 127, csplit = blockIdx.x >> 7;
    const int token0 = tile * 128, code0 = csplit * 2048;

    // register-resident Z frags for this wave's 32-token group
    f16x8 Zr[2][16];
    {
        const unsigned short* zb = zfrag + (size_t)(tile * 4 + wave) * 16384 + lane * 8;
#pragma unroll
        for (int lv = 0; lv < 2; ++lv)
#pragma unroll
            for (int ks = 0; ks < 16; ++ks)
                Zr[lv][ks] = *(const f16x8*)(zb + (lv * 16 + ks) * 512);
    }

    const int slv = wave >> 1, scg = wave & 1;   // this wave stages (level slv, code-group scg)

    float bv = 3.4e38f; int bi = 0;

    // prologue: chunk (ct=0, kc=0) -> buf 0; en_s[0]
#pragma unroll
    for (int ksl = 0; ksl < 4; ++ksl) {
        const unsigned short* sp = efrag +
            (size_t)(((csplit * 64 + scg) * 2 + slv) * 16 + ksl) * 512 + lane * 8;
        GLD16(sp, &E[0][(wave * 4 + ksl) * 512]);
    }
    if (tid < 64) en_s[0][tid] = enorm[code0 + tid];
    __syncthreads();

    for (int ct = 0; ct < 32; ++ct) {
        f32x16 acc_h[2], acc_l[2];
#pragma unroll
        for (int cg = 0; cg < 2; ++cg)
#pragma unroll
            for (int qq = 0; qq < 16; ++qq) { acc_h[cg][qq] = 0.f; acc_l[cg][qq] = 0.f; }

#pragma unroll
        for (int kc = 0; kc < 4; ++kc) {
            const int p = (ct * 4 + kc) & 1;
            if (!(ct == 31 && kc == 3)) {
                const int nch = ct * 4 + kc + 1;
                const int nct = nch >> 2, nkc = nch & 3;
                const int g = csplit * 64 + nct * 2 + scg;
#pragma unroll
                for (int ksl = 0; ksl < 4; ++ksl) {
                    const unsigned short* sp = efrag +
                        (size_t)((g * 2 + slv) * 16 + nkc * 4 + ksl) * 512 + lane * 8;
                    GLD16(sp, &E[p ^ 1][(wave * 4 + ksl) * 512]);
                }
            }
            if (kc == 0 && ct < 31 && tid < 64)
                en_s[(ct + 1) & 1][tid] = enorm[code0 + (ct + 1) * 64 + tid];

#pragma unroll
            for (int ksl = 0; ksl < 4; ++ksl) {
                const int ks = kc * 4 + ksl;
                f16x8 ae[2][2];
#pragma unroll
                for (int lv = 0; lv < 2; ++lv)
#pragma unroll
                    for (int cg = 0; cg < 2; ++cg)
                        ae[lv][cg] = *(const f16x8*)&E[p][((lv * 2 + cg) * 4 + ksl) * 512 + lane * 8];
#pragma unroll
                for (int cg = 0; cg < 2; ++cg) {
                    acc_h[cg] = __builtin_amdgcn_mfma_f32_32x32x16_f16(ae[0][cg], Zr[0][ks], acc_h[cg], 0, 0, 0);
                    acc_l[cg] = __builtin_amdgcn_mfma_f32_32x32x16_f16(ae[0][cg], Zr[1][ks], acc_l[cg], 0, 0, 0);
                    acc_l[cg] = __builtin_amdgcn_mfma_f32_32x32x16_f16(ae[1][cg], Zr[0][ks], acc_l[cg], 0, 0, 0);
                }
            }
            if (kc == 3) {
                // score = ||e||^2 - 2*(hi + lo/2048); per-lane running argmin (k ascending)
                const int rbase = 4 * (lane >> 5);
#pragma unroll
                for (int cg = 0; cg < 2; ++cg)
#pragma unroll
                    for (int r = 0; r < 16; ++r) {
                        const int cl = cg * 32 + (r & 3) + 8 * (r >> 2) + rbase;
                        const float s = en_s[ct & 1][cl] -
                            2.0f * (acc_h[cg][r] + acc_l[cg][r] * 4.8828125e-4f);
                        const int code = code0 + ct * 64 + cl;
                        if (s < bv) { bv = s; bi = code; }
                    }
            }
            __syncthreads();
        }
    }
    // lanes l and l^32 hold the same token (different code row-halves)
    {
        const float ov = __shfl_xor(bv, 32);
        const int   oi = __shfl_xor(bi, 32);
        if (ov < bv || (ov == bv && oi < bi)) { bv = ov; bi = oi; }
    }
    if (lane < 32) {
        const int n = token0 + wave * 32 + lane;
        pval[csplit * N_TOK + n] = bv;
        pidx[csplit * N_TOK + n] = bi;
    }
}

// ---- combine 4 code-split partials + per-code int counts ----
__global__ __launch_bounds__(256) void combine4_kernel(
    const float* __restrict__ pval, const int* __restrict__ pidx,
    int* __restrict__ idx_i, float* __restrict__ idx_f, int* __restrict__ cnt) {
    const int n = blockIdx.x * 256 + threadIdx.x;
    float bv = pval[n]; int bi = pidx[n];
#pragma unroll
    for (int s = 1; s < 4; ++s) {
        const float v = pval[s * N_TOK + n];
        const int i = pidx[s * N_TOK + n];
        if (v < bv || (v == bv && i < bi)) { bv = v; bi = i; }
    }
    idx_i[n] = bi;
    idx_f[n] = (float)bi;
    atomicAdd(&cnt[bi], 1);
}

// ---- exclusive scan of 8192 counts (single block) ----
__global__ __launch_bounds__(256) void scan_kernel(const int* __restrict__ cnt,
                                                   int* __restrict__ offs,
                                                   int* __restrict__ wpos) {
    __shared__ int part[256];
    const int tid = threadIdx.x;
    const int base = tid * 32;
    int loc[32];
    int s = 0;
#pragma unroll
    for (int j = 0; j < 32; ++j) { loc[j] = cnt[base + j]; s += loc[j]; }
    part[tid] = s;
    __syncthreads();
    for (int off = 1; off < 256; off <<= 1) {
        int v = 0;
        if (tid >= off) v = part[tid - off];
        __syncthreads();
        if (tid >= off) part[tid] += v;
        __syncthreads();
    }
    int run = (tid > 0) ? part[tid - 1] : 0;
#pragma unroll
    for (int j = 0; j < 32; ++j) {
        offs[base + j] = run;
        wpos[base + j] = run;
        run += loc[j];
    }
}

// ---- fused: scatter token ids (blocks 0-63) + cs/denom (blocks 64-95) ----
__global__ __launch_bounds__(256) void scatter_cs(
    const int* __restrict__ idx_i, int* __restrict__ wpos, int* __restrict__ tlist,
    const float* __restrict__ cluster_size, const int* __restrict__ cnt,
    float* __restrict__ cs, double* __restrict__ denom) {
    __shared__ double red[256];
    const int t = threadIdx.x, b = blockIdx.x;
    if (b < 64) {
        const int n = b * 256 + t;
        const int k = idx_i[n];
        tlist[atomicAdd(&wpos[k], 1)] = n;
    } else {
        const int k = (b - 64) * 256 + t;
        const float v = cluster_size[k] * 0.99f + 0.01f * (float)cnt[k] + 1e-5f;
        cs[k] = v;
        red[t] = (double)v;
        __syncthreads();
        for (int s2 = 128; s2; s2 >>= 1) {
            if (t < s2) red[t] += red[t + s2];
            __syncthreads();
        }
        if (t == 0) atomicAdd(denom, red[0]);
    }
}

// ---- fused: nema_finalize (blocks 0-2047, 4 codes each) + gather/loss (2048-3071) ----
__global__ __launch_bounds__(256) void nema_gather(
    const unsigned short* __restrict__ zfrag,
    const int* __restrict__ offs, const int* __restrict__ cnt, const int* __restrict__ tlist,
    const float* __restrict__ ema_w, const float* __restrict__ cs,
    const double* __restrict__ denom, float* __restrict__ ncs_out,
    float* __restrict__ nema_out, float* __restrict__ nemb_out,
    const float* __restrict__ z, const float* __restrict__ emb,
    const int* __restrict__ idx_i, float* __restrict__ out, float* __restrict__ loss_cell) {
    __shared__ float redf[256];
    const int t = threadIdx.x;
    if (blockIdx.x < 2048) {
        const int lane = t & 63, wave = t >> 6;
        const int k = blockIdx.x * 4 + wave;
        const int l31 = lane & 31, sel = lane >> 5;  // sel: 0 = hi loader, 1 = lo loader
        const int beg = offs[k], c = cnt[k];
        float acc[8] = {0.f, 0.f, 0.f, 0.f, 0.f, 0.f, 0.f, 0.f};
        for (int i = 0; i < c; ++i) {
            const int tok = tlist[beg + i];
            const int tg = tok >> 5, tl = tok & 31;
            // lane's dims: l31*8 .. +7  (piece: ks = l31>>1, khalf = l31&1)
            const uint4 v = *(const uint4*)(zfrag +
                (size_t)((tg * 2 + sel) * 16 + (l31 >> 1)) * 512 + (l31 & 1) * 256 + tl * 8);
            uint4 o;
            o.x = __shfl_xor((int)v.x, 32); o.y = __shfl_xor((int)v.y, 32);
            o.z = __shfl_xor((int)v.z, 32); o.w = __shfl_xor((int)v.w, 32);
            if (lane < 32) {
                const unsigned short* hp = (const unsigned short*)&v;
                const unsigned short* lp = (const unsigned short*)&o;
#pragma unroll
                for (int j = 0; j < 8; ++j) acc[j] += join_f16(hp[j], lp[j]);
            }
        }
        const float dn = (float)(*denom) + (float)K_CODES * 1e-5f;
        const float ncs = cs[k] / dn;
        if (lane == 0) ncs_out[k] = ncs;
        if (lane < 32) {
            const size_t off = ((size_t)k << 8) + l31 * 8;
#pragma unroll
            for (int j = 0; j < 8; ++j) {
                const float ne = ema_w[off + j] * 0.99f + 0.01f * acc[j];
                nema_out[off + j] = ne;
                nemb_out[off + j] = ne / ncs;
            }
        }
    } else {
        const int gb = blockIdx.x - 2048;
        const int n0 = (gb >> 2) * 64;
        const int dg = (gb & 3) * 64;
        const int b = n0 >> 10, hw0 = n0 & 1023;
        const int lane = t & 63, w = t >> 6;
        const int n = n0 + lane;
        const int k = idx_i[n];
        const float* zb = z + ((size_t)b << 18) + hw0 + lane;
        float* ob = out + ((size_t)b << 18) + hw0 + lane;
        float ls = 0.f;
#pragma unroll 4
        for (int d = dg + w; d < dg + 64; d += 4) {
            const float zv = zb[(size_t)d << 10];
            const float ev = emb[((size_t)k << 8) + d];
            ob[(size_t)d << 10] = ev;
            const float df = ev - zv;
            ls += df * df;
        }
        redf[t] = ls;
        __syncthreads();
        for (int s2 = 128; s2; s2 >>= 1) {
            if (t < s2) redf[t] += redf[t + s2];
            __syncthreads();
        }
        if (t == 0) atomicAdd(loss_cell, redf[0] * (0.25f / 4194304.0f));
    }
}

// ---------------- launch ----------------
extern "C" void kernel_launch(void* const* d_in, const int* in_sizes, int n_in,
                              void* d_out, int out_size, void* d_ws, size_t ws_size,
                              hipStream_t stream) {
    const float* z            = (const float*)d_in[0];
    const float* emb          = (const float*)d_in[1];
    const float* cluster_size = (const float*)d_in[2];
    const float* ema_w        = (const float*)d_in[3];
    float* out = (float*)d_out;
    char*  wsb = (char*)d_ws;

    unsigned short* zfrag = (unsigned short*)(wsb + WS_ZFRAG);
    unsigned short* efrag = (unsigned short*)(wsb + WS_EFRAG);
    float*  enorm  = (float*)(wsb + WS_ENORM);
    float*  pval   = (float*)(wsb + WS_PVAL);
    int*    pidx   = (int*)(wsb + WS_PIDX);
    int*    idx_i  = (int*)(wsb + WS_IDXI);
    int*    cnt    = (int*)(wsb + WS_CNT);
    float*  cs     = (float*)(wsb + WS_CS);
    int*    offs   = (int*)(wsb + WS_OFFS);
    int*    wpos   = (int*)(wsb + WS_WPOS);
    int*    tlist  = (int*)(wsb + WS_TLIST);
    double* denom  = (double*)(wsb + WS_DENOM);

    cvt_z_kernel<<<1024, 256, 0, stream>>>(z, zfrag, out + LOSS_OFF, denom);
    cvt_e_enorm<<<256, 256, 0, stream>>>(emb, efrag, enorm, cnt);
    argmin_mfma<<<512, 256, 0, stream>>>(zfrag, efrag, enorm, pval, pidx);
    combine4_kernel<<<N_TOK / 256, 256, 0, stream>>>(pval, pidx, idx_i,
                                                     out + IDX_OFF, cnt);
    scan_kernel<<<1, 256, 0, stream>>>(cnt, offs, wpos);
    scatter_cs<<<96, 256, 0, stream>>>(idx_i, wpos, tlist, cluster_size, cnt, cs, denom);
    nema_gather<<<3072, 256, 0, stream>>>(zfrag, offs, cnt, tlist, ema_w, cs, denom,
                                          out + NCS_OFF, out + NEMA_OFF, out + NEMB_OFF,
                                          z, emb, idx_i, out + OUT_OFF, out + LOSS_OFF);
}